// Round 15
// baseline (629.670 us; speedup 1.0000x reference)
//
#include <hip/hip_runtime.h>
#include <hip/hip_bf16.h>
#include <stdint.h>

#define N_ROWS 32768
#define K_CODES 8192
#define C_DIM 256
#define DECAYF 0.95f
#define COMMITF 0.25f
#define EPSF 1e-5f
#define RESC_EPS 0.045f
#define RESC_CAP 16384

// d_out layout (floats), reference return order
#define OFF_QUANT 0
#define OFF_ELOSS 8388608
#define OFF_PERP  8388609
#define OFF_UNIQ  8388610
#define OFF_NCB   8388611
#define OFF_NCNT  10485763
#define OFF_NW    10493955
#define OFF_IDX   12591107

typedef float f32x4 __attribute__((ext_vector_type(4)));
typedef int i32x4 __attribute__((ext_vector_type(4)));
typedef unsigned long long u64;
typedef unsigned int u32;

#define SWZ(r) ((((r) >> 2) & 7) << 2)

#if defined(__has_builtin)
#if __has_builtin(__builtin_amdgcn_global_load_lds)
#define HAVE_GLDS 1
#endif
#endif
#ifdef HAVE_GLDS
#define GLDS16(g, l) __builtin_amdgcn_global_load_lds( \
    (const __attribute__((address_space(1))) void*)(uintptr_t)(g), \
    (__attribute__((address_space(3))) void*)(uint32_t)(uintptr_t)(l), 16, 0, 0)
#else
#define GLDS16(g, l) do { *(float4*)(l) = *(const float4*)(g); } while (0)
#endif

__device__ __forceinline__ uint32_t fkey(float f) {
    uint32_t b = __float_as_uint(f);
    return b ^ ((uint32_t)((int32_t)b >> 31) | 0x80000000u);
}
// 14-bit fixed-point -> two signed i8 (h*128 + l), l in [-64,63]
__device__ __forceinline__ void enc8(float v, float inv, signed char& h, signed char& l) {
    int q = __float2int_rn(v * inv);
    q = q > 16319 ? 16319 : (q < -16320 ? -16320 : q);
    int hh = (q + 64) >> 7;
    h = (signed char)hh;
    l = (signed char)(q - (hh << 7));
}

// ---------------- per-block absmax of x (blocks 0-2047) and cb (2048-2559) ----------------
__global__ __launch_bounds__(256)
void kmax(const float* __restrict__ x, const float* __restrict__ cb, float* __restrict__ maxbuf) {
    const int bid = blockIdx.x, t = threadIdx.x;
    const float* src = bid < 2048 ? x : cb;
    const size_t base = bid < 2048 ? (size_t)bid * 4096 : (size_t)(bid - 2048) * 4096;
    float m = 0.f;
    #pragma unroll
    for (int i = 0; i < 4; ++i) {
        const float4 v = *(const float4*)(src + base + ((size_t)i * 256 + t) * 4);
        m = fmaxf(m, fmaxf(fmaxf(fabsf(v.x), fabsf(v.y)), fmaxf(fabsf(v.z), fabsf(v.w))));
    }
    #pragma unroll
    for (int off = 32; off; off >>= 1) m = fmaxf(m, __shfl_down(m, off));
    __shared__ float ps[4];
    if ((t & 63) == 0) ps[t >> 6] = m;
    __syncthreads();
    if (t == 0) maxbuf[bid] = fmaxf(fmaxf(ps[0], ps[1]), fmaxf(ps[2], ps[3]));
}

// ---------------- final scales + zero accumulators ----------------
__global__ void kscale(const float* __restrict__ maxbuf, float* __restrict__ scl,
                       float* __restrict__ counts, float* __restrict__ loss_arr,
                       unsigned* __restrict__ rcnt) {
    const int t = threadIdx.x;
    float mx = 0.f, me = 0.f;
    for (int i = t; i < 2048; i += 256) mx = fmaxf(mx, maxbuf[i]);
    for (int i = 2048 + t; i < 2560; i += 256) me = fmaxf(me, maxbuf[i]);
    #pragma unroll
    for (int off = 32; off; off >>= 1) {
        mx = fmaxf(mx, __shfl_down(mx, off));
        me = fmaxf(me, __shfl_down(me, off));
    }
    __shared__ float px[4], pe[4];
    if ((t & 63) == 0) { px[t >> 6] = mx; pe[t >> 6] = me; }
    __syncthreads();
    if (t == 0) {
        const float Sx = fmaxf(fmaxf(px[0], px[1]), fmaxf(px[2], px[3])) * (16384.f / 16320.f) + 1e-20f;
        const float Se = fmaxf(fmaxf(pe[0], pe[1]), fmaxf(pe[2], pe[3])) * (16384.f / 16320.f) + 1e-20f;
        scl[0] = Sx; scl[1] = Se; scl[2] = Sx * Se / 268435456.f;
        *rcnt = 0u;
    }
    for (int i = t; i < K_CODES; i += 256) counts[i] = 0.f;
    loss_arr[t] = 0.f;
}

// ---------------- encode cb (blocks 0-2047, + cnorm) and x (2048-4095, transpose) ----------------
__global__ __launch_bounds__(256)
void kprep(const float* __restrict__ cb, const float* __restrict__ x,
           signed char* __restrict__ Ah, signed char* __restrict__ Al,
           signed char* __restrict__ Bh, signed char* __restrict__ Bl,
           float* __restrict__ cnorm, const float* __restrict__ scl) {
    const int bid = blockIdx.x;
    const int t = threadIdx.x;
    if (bid < 2048) {
        const float inve = 16384.f / scl[1];
        const size_t i4 = ((size_t)bid * 256 + t) * 4;
        const float4 v = *(const float4*)(cb + i4);
        signed char h0, h1, h2, h3, l0, l1, l2, l3;
        enc8(v.x, inve, h0, l0); enc8(v.y, inve, h1, l1);
        enc8(v.z, inve, h2, l2); enc8(v.w, inve, h3, l3);
        *(char4*)(Bh + i4) = make_char4(h0, h1, h2, h3);
        *(char4*)(Bl + i4) = make_char4(l0, l1, l2, l3);
        float s = v.x * v.x + v.y * v.y + v.z * v.z + v.w * v.w;
        #pragma unroll
        for (int off = 32; off; off >>= 1) s += __shfl_down(s, off);
        if ((t & 63) == 0) cnorm[i4 >> 8] = s;
    } else {
        const float invx = 16384.f / scl[0];
        __shared__ float xt[64][65];
        const int xb_id = bid - 2048;       // 8 b * 4 ct * 64 st = 2048
        const int st = xb_id & 63;
        const int ct = (xb_id >> 6) & 3;
        const int b  = xb_id >> 8;
        const float* xb = x + ((size_t)b * C_DIM + ct * 64) * 4096 + st * 64;
        {
            const int s_l = t & 63, c0 = t >> 6;
            #pragma unroll
            for (int cc = 0; cc < 16; ++cc) {
                int c_l = cc * 4 + c0;
                xt[c_l][s_l] = xb[(size_t)c_l * 4096 + s_l];
            }
        }
        __syncthreads();
        const int c2 = (t & 31) * 2;
        const int s0 = t >> 5;
        #pragma unroll
        for (int ww = 0; ww < 8; ++ww) {
            int s_o = ww * 8 + s0;
            signed char h0, l0, h1, l1;
            enc8(xt[c2][s_o], invx, h0, l0);
            enc8(xt[c2 + 1][s_o], invx, h1, l1);
            size_t off = ((size_t)(b * 4096 + st * 64 + s_o)) * C_DIM + ct * 64 + c2;
            *(char2*)(Ah + off) = make_char2(h0, h1);
            *(char2*)(Al + off) = make_char2(l0, l1);
        }
    }
}

// ---------------- i8 MFMA distance GEMM + per-row top-2 argmin ----------------
// 128x256 tile, 8 waves (2Mx4N), per-wave 64x64 (acc[4][4]).
// BK=64 i8; fully-unrolled 12 K-tiles: 0-3 (h,h), <<7, 4-7 (h,l), 8-11 (l,h).
// LDS 48KB dbuf, 2 blocks/CU. Integer-domain epilogue (exact i32 compare).
__global__ __launch_bounds__(512, 4)
void kargmin_i8(const signed char* __restrict__ Ah, const signed char* __restrict__ Al,
                const signed char* __restrict__ Bh, const signed char* __restrict__ Bl,
                const float* __restrict__ cnorm, const float* __restrict__ scl,
                u64* __restrict__ wsmin) {
    __shared__ unsigned char As[2][128 * 64];   // 8KB x2
    __shared__ unsigned char Bs[2][256 * 64];   // 16KB x2

    const int t = threadIdx.x;
    const int lane = t & 63;
    const int wid = t >> 6;
    const int xcd = blockIdx.x & 7;
    const int ii = blockIdx.x >> 3;              // 0..1023 within XCD
    const int ntile = xcd * 4 + (ii & 3);        // 0..31
    const int mtile = ii >> 2;                   // 0..255
    const int m0 = mtile * 128;
    const int n0 = ntile * 256;
    const int wr = wid >> 2;                     // 0..1
    const int wc = wid & 3;                      // 0..3
    const int wm = wr * 64;
    const int wn = wc * 64;
    const int lm = lane & 15;
    const int lh = lane >> 4;

    i32x4 acc[4][4];
    #pragma unroll
    for (int i = 0; i < 4; ++i)
        #pragma unroll
        for (int j = 0; j < 4; ++j) acc[i][j] = (i32x4){0, 0, 0, 0};

    // staging: rows of 64B = 4 slots of 16B; swizzle slot ^= (row&3)^((row>>2)&3)
    const int sAr = t >> 2;          // A row 0..127 (B rows sAr and 128+sAr, same swizzle)
    const int ssl = t & 3;
    const int gsA = ssl ^ (sAr & 3) ^ ((sAr >> 2) & 3);
    const size_t thr = (size_t)sAr * 256 + (size_t)gsA * 16;

    const signed char* pA0 = Ah + (size_t)m0 * 256 + thr;   // segs 0,1
    const signed char* pA1 = Al + (size_t)m0 * 256 + thr;   // seg 2
    const signed char* pB0 = Bh + (size_t)n0 * 256 + thr;   // segs 0,2
    const signed char* pB1 = Bl + (size_t)n0 * 256 + thr;   // seg 1

#define STAGE(PA, PB, KOFF, BUF) do { \
        GLDS16((PA) + (KOFF), &As[BUF][t * 16]); \
        GLDS16((PB) + (KOFF), &Bs[BUF][t * 16]); \
        GLDS16((PB) + 32768 + (KOFF), &Bs[BUF][(512 + t) * 16]); \
    } while (0)

    const int rboff = (lh ^ (lm & 3) ^ ((lm >> 2) & 3)) * 16;

#define TILE(CUR, PF, FOLD) do { \
        PF; \
        i32x4 a_[4], b_[4]; \
        _Pragma("unroll") \
        for (int j = 0; j < 4; ++j) \
            b_[j] = *(const i32x4*)&Bs[CUR][(wn + j * 16 + lm) * 64 + rboff]; \
        _Pragma("unroll") \
        for (int i = 0; i < 4; ++i) \
            a_[i] = *(const i32x4*)&As[CUR][(wm + i * 16 + lm) * 64 + rboff]; \
        _Pragma("unroll") \
        for (int i = 0; i < 4; ++i) \
            _Pragma("unroll") \
            for (int j = 0; j < 4; ++j) \
                acc[i][j] = __builtin_amdgcn_mfma_i32_16x16x64_i8(a_[i], b_[j], acc[i][j], 0, 0, 0); \
        FOLD; \
        __syncthreads(); \
    } while (0)

#define FOLDACC \
        _Pragma("unroll") \
        for (int i = 0; i < 4; ++i) \
            _Pragma("unroll") \
            for (int j = 0; j < 4; ++j) \
                acc[i][j] = acc[i][j] << 7

    STAGE(pA0, pB0, 0, 0);
    __syncthreads();
    TILE(0, STAGE(pA0, pB0, 64, 1), (void)0);
    TILE(1, STAGE(pA0, pB0, 128, 0), (void)0);
    TILE(0, STAGE(pA0, pB0, 192, 1), (void)0);
    TILE(1, STAGE(pA0, pB1, 0, 0), FOLDACC);     // H done -> acc = 128*H
    TILE(0, STAGE(pA0, pB1, 64, 1), (void)0);
    TILE(1, STAGE(pA0, pB1, 128, 0), (void)0);
    TILE(0, STAGE(pA0, pB1, 192, 1), (void)0);
    TILE(1, STAGE(pA1, pB0, 0, 0), (void)0);
    TILE(0, STAGE(pA1, pB0, 64, 1), (void)0);
    TILE(1, STAGE(pA1, pB0, 128, 0), (void)0);
    TILE(0, STAGE(pA1, pB0, 192, 1), (void)0);
    TILE(1, (void)0, (void)0);
#undef TILE
#undef STAGE
#undef FOLDACC

    // integer-domain epilogue: units v = cni - acc (monotone with dist); exact i32
    const float invu = 1.f / (256.f * scl[2]);
    int cni[4];
    #pragma unroll
    for (int j = 0; j < 4; ++j)
        cni[j] = (int)rintf(cnorm[n0 + wn + j * 16 + lm] * invu);

    u64* redbuf = (u64*)&As[0][0];   // 128 rows x 4 wc x 2 u64 = 8KB
    #pragma unroll
    for (int i = 0; i < 4; ++i) {
        u64 p1[4], p2[4];
        #pragma unroll
        for (int r = 0; r < 4; ++r) {
            u64 b1 = ~0ull, b2 = ~0ull;
            #pragma unroll
            for (int j = 0; j < 4; ++j) {
                const u32 v = (u32)(cni[j] - acc[i][j][r] + 0x40000000);
                u64 pk = ((u64)v << 32) | (unsigned)(n0 + wn + j * 16 + lm);
                if (pk < b1) { b2 = b1; b1 = pk; }
                else if (pk < b2) b2 = pk;
            }
            p1[r] = b1; p2[r] = b2;
        }
        #pragma unroll
        for (int off = 1; off < 16; off <<= 1) {
            #pragma unroll
            for (int r = 0; r < 4; ++r) {
                u64 o1 = __shfl_xor(p1[r], off);
                u64 o2 = __shfl_xor(p2[r], off);
                u64 lo = p1[r] < o1 ? p1[r] : o1;
                u64 hi = p1[r] < o1 ? o1 : p1[r];
                u64 mn2 = p2[r] < o2 ? p2[r] : o2;
                p1[r] = lo;
                p2[r] = hi < mn2 ? hi : mn2;
            }
        }
        if (lm == 0) {
            #pragma unroll
            for (int r = 0; r < 4; ++r) {
                const int rl = wm + i * 16 + lh * 4 + r;   // 0..127
                redbuf[rl * 8 + wc * 2 + 0] = p1[r];
                redbuf[rl * 8 + wc * 2 + 1] = p2[r];
            }
        }
    }
    __syncthreads();
    if (t < 128) {
        u64 m1 = ~0ull, m2 = ~0ull;
        #pragma unroll
        for (int w = 0; w < 4; ++w) {
            u64 a1 = redbuf[t * 8 + w * 2 + 0];
            u64 a2 = redbuf[t * 8 + w * 2 + 1];
            u64 lo = m1 < a1 ? m1 : a1;
            u64 hi = m1 < a1 ? a1 : m1;
            u64 mn2 = m2 < a2 ? m2 : a2;
            m1 = lo;
            m2 = hi < mn2 ? hi : mn2;
        }
        size_t o = ((size_t)(m0 + t) * 32 + ntile) * 2;
        wsmin[o] = m1; wsmin[o + 1] = m2;
    }
}

// ---------------- combine per-ntile mins; histogram; flag near-ties ----------------
__global__ void kcombine(const u64* __restrict__ wsmin, float* __restrict__ idxf,
                         unsigned* __restrict__ rcnt, unsigned* __restrict__ rrows,
                         uint2* __restrict__ rpair, float* __restrict__ counts,
                         const float* __restrict__ scl) {
    const int row = blockIdx.x * 256 + threadIdx.x;
    const u64* p = wsmin + (size_t)row * 64;
    u64 m1 = ~0ull, m2 = ~0ull;
    for (int i = 0; i < 64; i += 2) {
        u64 a = p[i], b = p[i + 1];
        u64 lo = a < m1 ? a : m1;
        u64 hi = a < m1 ? m1 : a;
        u64 c = m2 < b ? m2 : b;
        m1 = lo;
        m2 = hi < c ? hi : c;
    }
    const int k = (int)(unsigned)(m1 & 0xffffffffu);
    idxf[row] = (float)k;
    atomicAdd(&counts[k], 1.0f);
    const float du = 256.f * scl[2];
    const float d1 = (float)((int)(u32)(m1 >> 32) - 0x40000000) * du;
    const float d2 = (float)((int)(u32)(m2 >> 32) - 0x40000000) * du;
    if (d2 - d1 < RESC_EPS) {
        unsigned slot = atomicAdd(rcnt, 1u);
        if (slot < RESC_CAP) {
            rrows[slot] = (unsigned)row;
            rpair[slot] = make_uint2((unsigned)k, (unsigned)(m2 & 0xffffffffu));
        }
    }
}

// ---------------- exact fp32 pair re-score (wave per flagged row) ----------------
__global__ __launch_bounds__(256)
void krescue2(const float* __restrict__ x, const float* __restrict__ cb,
              const float* __restrict__ cnorm, const unsigned* __restrict__ rcnt,
              const unsigned* __restrict__ rrows, const uint2* __restrict__ rpair,
              float* __restrict__ idxf, float* __restrict__ counts) {
    const int lane = threadIdx.x & 63;
    const int wv = threadIdx.x >> 6;
    unsigned cnt = *rcnt; if (cnt > RESC_CAP) cnt = RESC_CAP;
    for (unsigned i = blockIdx.x * 4 + wv; i < cnt; i += gridDim.x * 4) {
        const int row = (int)rrows[i];
        const uint2 kk = rpair[i];
        const int b = row >> 12, s = row & 4095;
        float d1 = 0.f, d2 = 0.f;
        #pragma unroll
        for (int q = 0; q < 4; ++q) {
            const int c = lane + q * 64;
            const float xv = x[((size_t)(b * 256 + c)) * 4096 + s];
            d1 = fmaf(xv, cb[(size_t)kk.x * 256 + c], d1);
            d2 = fmaf(xv, cb[(size_t)kk.y * 256 + c], d2);
        }
        #pragma unroll
        for (int off = 32; off; off >>= 1) {
            d1 += __shfl_down(d1, off);
            d2 += __shfl_down(d2, off);
        }
        if (lane == 0) {
            const float dist1 = fmaf(-2.f, d1, cnorm[kk.x]);
            const float dist2 = fmaf(-2.f, d2, cnorm[kk.y]);
            const u64 p1 = ((u64)fkey(dist1) << 32) | kk.x;
            const u64 p2 = ((u64)fkey(dist2) << 32) | kk.y;
            const int knew = (int)(unsigned)((p1 < p2 ? p1 : p2) & 0xffffffffu);
            const int kold = (int)kk.x;
            if (knew != kold) {
                atomicAdd(&counts[kold], -1.0f);
                atomicAdd(&counts[knew], 1.0f);
                idxf[row] = (float)knew;
            }
        }
    }
}

// ---------------- CSR build: scan / scatter ----------------
__global__ void kscan(const float* __restrict__ counts, unsigned* __restrict__ off,
                      unsigned* __restrict__ cursor) {
    __shared__ unsigned part[256];
    const int t = threadIdx.x;
    unsigned local[32];
    unsigned s = 0;
    #pragma unroll
    for (int i = 0; i < 32; ++i) { local[i] = s; s += (unsigned)counts[t * 32 + i]; }
    part[t] = s;
    __syncthreads();
    if (t == 0) {
        unsigned run = 0;
        for (int i = 0; i < 256; ++i) { unsigned v = part[i]; part[i] = run; run += v; }
    }
    __syncthreads();
    const unsigned base = part[t];
    #pragma unroll
    for (int i = 0; i < 32; ++i) {
        unsigned o = base + local[i];
        off[t * 32 + i] = o;
        cursor[t * 32 + i] = o;
    }
}

__global__ void kscatter(const float* __restrict__ idxf, unsigned* __restrict__ cursor,
                         unsigned* __restrict__ rowlist) {
    const int n = blockIdx.x * 256 + threadIdx.x;
    const int k = (int)idxf[n];
    unsigned pos = atomicAdd(&cursor[k], 1u);
    rowlist[pos] = (unsigned)n;
}

// ---------------- dw = segment_sum(x) via CSR, exact-int from i8 planes ----------------
__global__ void kdw(const signed char* __restrict__ Ah, const signed char* __restrict__ Al,
                    const float* __restrict__ counts, const unsigned* __restrict__ off,
                    const unsigned* __restrict__ rowlist, const float* __restrict__ scl,
                    float* __restrict__ dwout) {
    const int k = blockIdx.x;
    const int lane = threadIdx.x;   // 64
    const int cnt = (int)counts[k];
    const unsigned base = off[k];
    int ax = 0, ay = 0, az = 0, aw = 0;
    for (int i = 0; i < cnt; ++i) {
        const unsigned row = rowlist[base + i];
        const char4 h = *(const char4*)(Ah + (size_t)row * C_DIM + lane * 4);
        const char4 l = *(const char4*)(Al + (size_t)row * C_DIM + lane * 4);
        ax += h.x * 128 + l.x;
        ay += h.y * 128 + l.y;
        az += h.z * 128 + l.z;
        aw += h.w * 128 + l.w;
    }
    const float sxf = scl[0] * (1.f / 16384.f);
    float4 o;
    o.x = (float)ax * sxf; o.y = (float)ay * sxf;
    o.z = (float)az * sxf; o.w = (float)aw * sxf;
    *(float4*)(dwout + (size_t)k * C_DIM + lane * 4) = o;
}

// ---------------- quantize (gather-transpose) + e_loss ----------------
__global__ __launch_bounds__(256)
void kquant2(const float* __restrict__ x, const float* __restrict__ cb,
             const float* __restrict__ idxf, float* __restrict__ qout,
             float* __restrict__ loss_arr) {
    __shared__ int ki[64];
    __shared__ float cbt[64][257];
    const int t = threadIdx.x;
    const int bid = blockIdx.x;
    const int chunk = bid & 63;
    const int b = bid >> 6;
    const int s0 = chunk * 64;
    if (t < 64) ki[t] = (int)idxf[b * 4096 + s0 + t];
    __syncthreads();
    {
        const int lane = t & 63;
        const int rr = t >> 6;
        #pragma unroll
        for (int p = 0; p < 16; ++p) {
            const int r = p * 4 + rr;
            const float4 v = *(const float4*)(cb + (size_t)ki[r] * C_DIM + lane * 4);
            cbt[r][lane * 4 + 0] = v.x;
            cbt[r][lane * 4 + 1] = v.y;
            cbt[r][lane * 4 + 2] = v.z;
            cbt[r][lane * 4 + 3] = v.w;
        }
    }
    __syncthreads();
    const int sg = t & 15;
    const int c0 = t >> 4;
    float lsum = 0.f;
    #pragma unroll
    for (int cc = 0; cc < 16; ++cc) {
        const int c = cc * 16 + c0;
        const size_t go = ((size_t)b * C_DIM + c) * 4096 + s0 + sg * 4;
        const float4 xv = *(const float4*)(x + go);
        float qx = cbt[sg * 4 + 0][c];
        float qy = cbt[sg * 4 + 1][c];
        float qz = cbt[sg * 4 + 2][c];
        float qw = cbt[sg * 4 + 3][c];
        float4 st;
        st.x = xv.x + (qx - xv.x);
        st.y = xv.y + (qy - xv.y);
        st.z = xv.z + (qz - xv.z);
        st.w = xv.w + (qw - xv.w);
        *(float4*)(qout + go) = st;
        float dx = qx - xv.x, dy = qy - xv.y, dz = qz - xv.z, dw_ = qw - xv.w;
        lsum += dx * dx + dy * dy + dz * dz + dw_ * dw_;
    }
    #pragma unroll
    for (int off = 32; off; off >>= 1) lsum += __shfl_down(lsum, off);
    __shared__ float ps[4];
    if ((t & 63) == 0) ps[t >> 6] = lsum;
    __syncthreads();
    if (t == 0) atomicAdd(&loss_arr[bid & 255], ps[0] + ps[1] + ps[2] + ps[3]);
}

// ---------------- EMA finalize + stats (fused; block K_CODES does stats) ----------------
__global__ void kfinal2(const float* __restrict__ ema_c, const float* __restrict__ ema_w,
                        const float* __restrict__ counts, float* __restrict__ dw,
                        float* __restrict__ ncb, float* __restrict__ ncnt_out,
                        const float* __restrict__ loss_arr, float* __restrict__ out) {
    const int k = blockIdx.x;
    const int t = threadIdx.x;
    if (k < K_CODES) {
        const float ncnt = (DECAYF * ema_c[k] + (1.f - DECAYF) * counts[k] + EPSF)
                           / (8.f + (float)K_CODES * EPSF) * 8.f;
        const size_t o = (size_t)k * C_DIM + t;
        const float nwv = DECAYF * ema_w[o] + (1.f - DECAYF) * dw[o];
        dw[o]  = nwv;
        ncb[o] = nwv / ncnt;
        if (t == 0) ncnt_out[k] = ncnt;
    } else {
        float nz = 0.f, s = 0.f;
        for (int kk = t; kk < K_CODES; kk += 256) {
            float cnt = counts[kk];
            if (cnt != 0.f) nz += 1.f;
            float p = cnt * (1.f / 32768.f);
            s += p * logf(p + 1e-10f);
        }
        float ls = loss_arr[t];
        #pragma unroll
        for (int off = 32; off; off >>= 1) {
            s  += __shfl_down(s, off);
            nz += __shfl_down(nz, off);
            ls += __shfl_down(ls, off);
        }
        __shared__ float ss[4], zz[4], ll[4];
        const int wid = t >> 6, lane = t & 63;
        if (lane == 0) { ss[wid] = s; zz[wid] = nz; ll[wid] = ls; }
        __syncthreads();
        if (t == 0) {
            float st = ss[0] + ss[1] + ss[2] + ss[3];
            float zt = zz[0] + zz[1] + zz[2] + zz[3];
            float lt = ll[0] + ll[1] + ll[2] + ll[3];
            out[OFF_ELOSS] = COMMITF * lt / 8388608.f;
            out[OFF_PERP]  = expf(-st);
            out[OFF_UNIQ]  = zt;
        }
    }
}

// ======= fallback fp32 path (used only if ws too small) =======
__global__ void knorm(const float* __restrict__ cb, float* __restrict__ cnorm) {
    const int wid  = threadIdx.x >> 6;
    const int lane = threadIdx.x & 63;
    const int row  = blockIdx.x * 4 + wid;
    const float4 v = *(const float4*)(cb + (size_t)row * C_DIM + lane * 4);
    float s = v.x * v.x + v.y * v.y + v.z * v.z + v.w * v.w;
    #pragma unroll
    for (int off = 32; off; off >>= 1) s += __shfl_down(s, off);
    if (lane == 0) cnorm[row] = s;
}

__launch_bounds__(256, 1)
__global__ void kargmin_fp32(const float* __restrict__ x, const float* __restrict__ cb,
                             const float* __restrict__ cnorm, float* __restrict__ idxf) {
    __shared__ float xs[64][256];
    __shared__ float es[64][256];
    const int t  = threadIdx.x;
    const int n0 = blockIdx.x * 64;
    const int b  = n0 >> 12;
    const int s0 = n0 & 4095;
    {
        const int r  = t & 63;
        const int c0 = t >> 6;
        const float* xb = x + (size_t)b * C_DIM * 4096 + s0 + r;
        const int sw = SWZ(r);
        #pragma unroll 8
        for (int cc = 0; cc < 64; ++cc) {
            int c = cc * 4 + c0;
            xs[r][c ^ sw] = xb[(size_t)c * 4096];
        }
    }
    const int mg  = t >> 4;
    const int ng  = t & 15;
    const int m0  = mg * 4;
    const int nn0 = ng * 4;
    const int swm = SWZ(m0);
    const int swn = SWZ(nn0);
    float minv[4] = {1e30f, 1e30f, 1e30f, 1e30f};
    int   mini[4] = {0, 0, 0, 0};
    for (int k0 = 0; k0 < K_CODES; k0 += 64) {
        __syncthreads();
        {
            const int lane = t & 63;
            const int cw   = t >> 6;
            #pragma unroll
            for (int p = 0; p < 16; ++p) {
                int code = p * 4 + cw;
                float4 v = *(const float4*)(cb + (size_t)(k0 + code) * C_DIM + lane * 4);
                *(float4*)&es[code][(lane * 4) ^ SWZ(code)] = v;
            }
        }
        float cn[4];
        #pragma unroll
        for (int j = 0; j < 4; ++j) cn[j] = cnorm[k0 + nn0 + j];
        __syncthreads();
        float acc[4][4];
        #pragma unroll
        for (int i = 0; i < 4; ++i)
            #pragma unroll
            for (int j = 0; j < 4; ++j) acc[i][j] = 0.f;
        #pragma unroll 4
        for (int c = 0; c < C_DIM; c += 4) {
            float4 xa[4], eb[4];
            #pragma unroll
            for (int i = 0; i < 4; ++i) xa[i] = *(const float4*)&xs[m0 + i][c ^ swm];
            #pragma unroll
            for (int j = 0; j < 4; ++j) eb[j] = *(const float4*)&es[nn0 + j][c ^ swn];
            #pragma unroll
            for (int i = 0; i < 4; ++i)
                #pragma unroll
                for (int j = 0; j < 4; ++j)
                    acc[i][j] += xa[i].x * eb[j].x + xa[i].y * eb[j].y +
                                 xa[i].z * eb[j].z + xa[i].w * eb[j].w;
        }
        #pragma unroll
        for (int j = 0; j < 4; ++j) {
            const int kg = k0 + nn0 + j;
            #pragma unroll
            for (int i = 0; i < 4; ++i) {
                float dist = fmaf(-2.f, acc[i][j], cn[j]);
                if (dist < minv[i]) { minv[i] = dist; mini[i] = kg; }
            }
        }
    }
    #pragma unroll
    for (int off = 1; off < 16; off <<= 1) {
        #pragma unroll
        for (int i = 0; i < 4; ++i) {
            float ov = __shfl_xor(minv[i], off);
            int   oi = __shfl_xor(mini[i], off);
            if (ov < minv[i] || (ov == minv[i] && oi < mini[i])) { minv[i] = ov; mini[i] = oi; }
        }
    }
    if (ng == 0) {
        #pragma unroll
        for (int i = 0; i < 4; ++i) idxf[n0 + m0 + i] = (float)mini[i];
    }
}

__global__ void kquant_legacy(const float* __restrict__ x, const float* __restrict__ cb,
                              const float* __restrict__ idxf, float* __restrict__ qout,
                              float* __restrict__ dw, float* __restrict__ counts,
                              float* __restrict__ loss_arr) {
    const int t   = threadIdx.x;
    const int bid = blockIdx.x;
    const int sc  = bid & 15;
    const int c   = (bid >> 4) & 255;
    const int b   = bid >> 12;
    const int s   = sc * 256 + t;
    const int n   = b * 4096 + s;
    const int k   = (int)idxf[n];
    const size_t xoff = ((size_t)b * C_DIM + c) * 4096 + s;
    const float xv = x[xoff];
    const float q  = cb[(size_t)k * C_DIM + c];
    qout[xoff] = xv + (q - xv);
    atomicAdd(&dw[(size_t)k * C_DIM + c], xv);
    if (c == 0) atomicAdd(&counts[k], 1.0f);
    float d = q - xv;
    float p = d * d;
    #pragma unroll
    for (int off = 32; off; off >>= 1) p += __shfl_down(p, off);
    __shared__ float ps[4];
    if ((t & 63) == 0) ps[t >> 6] = p;
    __syncthreads();
    if (t == 0) atomicAdd(&loss_arr[bid & 255], ps[0] + ps[1] + ps[2] + ps[3]);
}

__global__ void kstats_legacy(const float* __restrict__ counts, const float* __restrict__ loss_arr,
                              float* __restrict__ out) {
    const int t = threadIdx.x;
    float nz = 0.f, s = 0.f;
    for (int k = t; k < K_CODES; k += 256) {
        float cnt = counts[k];
        if (cnt != 0.f) nz += 1.f;
        float p = cnt * (1.f / 32768.f);
        s += p * logf(p + 1e-10f);
    }
    float ls = loss_arr[t];
    #pragma unroll
    for (int off = 32; off; off >>= 1) {
        s  += __shfl_down(s, off);
        nz += __shfl_down(nz, off);
        ls += __shfl_down(ls, off);
    }
    __shared__ float ss[4], zz[4], ll[4];
    const int wid = t >> 6, lane = t & 63;
    if (lane == 0) { ss[wid] = s; zz[wid] = nz; ll[wid] = ls; }
    __syncthreads();
    if (t == 0) {
        out[OFF_ELOSS] = COMMITF * (ll[0] + ll[1] + ll[2] + ll[3]) / 8388608.f;
        out[OFF_PERP]  = expf(-(ss[0] + ss[1] + ss[2] + ss[3]));
        out[OFF_UNIQ]  = zz[0] + zz[1] + zz[2] + zz[3];
    }
}

__global__ void kfinal_legacy(const float* __restrict__ ema_c, const float* __restrict__ ema_w,
                              float* __restrict__ counts, float* __restrict__ dw,
                              float* __restrict__ ncb) {
    const int k = blockIdx.x;
    const int c = threadIdx.x;
    const float cnt  = counts[k];
    const float ncnt = (DECAYF * ema_c[k] + (1.f - DECAYF) * cnt + EPSF)
                       / (8.f + (float)K_CODES * EPSF) * 8.f;
    const size_t o = (size_t)k * C_DIM + c;
    const float nw = DECAYF * ema_w[o] + (1.f - DECAYF) * dw[o];
    __syncthreads();
    dw[o]  = nw;
    ncb[o] = nw / ncnt;
    if (c == 0) counts[k] = ncnt;
}

extern "C" void kernel_launch(void* const* d_in, const int* in_sizes, int n_in,
                              void* d_out, int out_size, void* d_ws, size_t ws_size,
                              hipStream_t stream) {
    const float* x     = (const float*)d_in[0];
    const float* cb    = (const float*)d_in[1];
    const float* ema_c = (const float*)d_in[2];
    const float* ema_w = (const float*)d_in[3];
    float* out = (float*)d_out;

    float* qout = out + OFF_QUANT;
    float* ncb  = out + OFF_NCB;
    float* ncnt = out + OFF_NCNT;
    float* nw   = out + OFF_NW;
    float* idxf = out + OFF_IDX;

    const size_t szA = (size_t)N_ROWS * C_DIM;    // 8388608 bytes per plane
    const size_t szB = (size_t)K_CODES * C_DIM;   // 2097152
    const size_t fcount = 8192 + 256 + 8192 + 4 + 2560;
    const size_t need = 2 * szA + 2 * szB + fcount * 4
                      + RESC_CAP * 8 + RESC_CAP * 4 + 4 + 8192 * 4 * 2 + 32768 * 4 + 64;
    const bool use_i8 = ws_size >= need;

    if (use_i8) {
        signed char* Ah = (signed char*)d_ws;
        signed char* Al = Ah + szA;
        signed char* Bh = Al + szA;
        signed char* Bl = Bh + szB;
        float* fbase      = (float*)(Bl + szB);
        float* cnorm      = fbase;
        float* loss_arr   = fbase + 8192;
        float* counts_raw = fbase + 8448;
        float* scl        = fbase + 16640;
        float* maxbuf     = fbase + 16644;
        uint2* rpair      = (uint2*)(fbase + fcount);
        unsigned* rrows   = (unsigned*)(rpair + RESC_CAP);
        unsigned* rcnt    = rrows + RESC_CAP;
        unsigned* off     = rcnt + 1;
        unsigned* cursor  = off + K_CODES;
        unsigned* rowlist = cursor + K_CODES;
        u64* wsmin = (u64*)(out + OFF_QUANT);   // 16.8 MB, consumed before kquant2 writes qout

        kmax<<<2560, 256, 0, stream>>>(x, cb, maxbuf);
        kscale<<<1, 256, 0, stream>>>(maxbuf, scl, counts_raw, loss_arr, rcnt);
        kprep<<<4096, 256, 0, stream>>>(cb, x, Ah, Al, Bh, Bl, cnorm, scl);
        kargmin_i8<<<8192, 512, 0, stream>>>(Ah, Al, Bh, Bl, cnorm, scl, wsmin);
        kcombine<<<N_ROWS / 256, 256, 0, stream>>>(wsmin, idxf, rcnt, rrows, rpair, counts_raw, scl);
        krescue2<<<256, 256, 0, stream>>>(x, cb, cnorm, rcnt, rrows, rpair, idxf, counts_raw);
        kscan<<<1, 256, 0, stream>>>(counts_raw, off, cursor);
        kscatter<<<N_ROWS / 256, 256, 0, stream>>>(idxf, cursor, rowlist);
        kdw<<<K_CODES, 64, 0, stream>>>(Ah, Al, counts_raw, off, rowlist, scl, nw);
        kquant2<<<512, 256, 0, stream>>>(x, cb, idxf, qout, loss_arr);
        kfinal2<<<K_CODES + 1, C_DIM, 0, stream>>>(ema_c, ema_w, counts_raw, nw, ncb, ncnt,
                                                   loss_arr, out);
    } else {
        float* cnorm = (float*)d_ws;
        float* loss_arr = cnorm + K_CODES;
        hipMemsetAsync(ncnt, 0, K_CODES * sizeof(float), stream);
        hipMemsetAsync(nw, 0, (size_t)K_CODES * C_DIM * sizeof(float), stream);
        hipMemsetAsync(loss_arr, 0, 256 * sizeof(float), stream);
        knorm<<<K_CODES / 4, 256, 0, stream>>>(cb, cnorm);
        kargmin_fp32<<<N_ROWS / 64, 256, 0, stream>>>(x, cb, cnorm, idxf);
        kquant_legacy<<<32768, 256, 0, stream>>>(x, cb, idxf, qout, nw, ncnt, loss_arr);
        kstats_legacy<<<1, 256, 0, stream>>>(ncnt, loss_arr, out);
        kfinal_legacy<<<K_CODES, C_DIM, 0, stream>>>(ema_c, ema_w, ncnt, nw, ncb);
    }
}

// Round 16
// 571.878 us; speedup vs baseline: 1.1011x; 1.1011x over previous
//
#include <hip/hip_runtime.h>
#include <hip/hip_bf16.h>
#include <stdint.h>

#define N_ROWS 32768
#define K_CODES 8192
#define C_DIM 256
#define DECAYF 0.95f
#define COMMITF 0.25f
#define EPSF 1e-5f
#define RESC_KEYGAP 2u
#define RESC_CAP 16384

// d_out layout (floats), reference return order
#define OFF_QUANT 0
#define OFF_ELOSS 8388608
#define OFF_PERP  8388609
#define OFF_UNIQ  8388610
#define OFF_NCB   8388611
#define OFF_NCNT  10485763
#define OFF_NW    10493955
#define OFF_IDX   12591107

typedef float f32x4 __attribute__((ext_vector_type(4)));
typedef int i32x4 __attribute__((ext_vector_type(4)));
typedef unsigned long long u64;
typedef unsigned int u32;

#define SWZ(r) ((((r) >> 2) & 7) << 2)

#if defined(__has_builtin)
#if __has_builtin(__builtin_amdgcn_global_load_lds)
#define HAVE_GLDS 1
#endif
#endif
#ifdef HAVE_GLDS
#define GLDS16(g, l) __builtin_amdgcn_global_load_lds( \
    (const __attribute__((address_space(1))) void*)(uintptr_t)(g), \
    (__attribute__((address_space(3))) void*)(uint32_t)(uintptr_t)(l), 16, 0, 0)
#else
#define GLDS16(g, l) do { *(float4*)(l) = *(const float4*)(g); } while (0)
#endif

__device__ __forceinline__ uint32_t fkey(float f) {
    uint32_t b = __float_as_uint(f);
    return b ^ ((uint32_t)((int32_t)b >> 31) | 0x80000000u);
}
// 14-bit fixed-point -> two signed i8 (h*128 + l), l in [-64,63]
__device__ __forceinline__ void enc8(float v, float inv, signed char& h, signed char& l) {
    int q = __float2int_rn(v * inv);
    q = q > 16319 ? 16319 : (q < -16320 ? -16320 : q);
    int hh = (q + 64) >> 7;
    h = (signed char)hh;
    l = (signed char)(q - (hh << 7));
}

// ---------------- per-block absmax of x (blocks 0-2047) and cb (2048-2559) ----------------
__global__ __launch_bounds__(256)
void kmax(const float* __restrict__ x, const float* __restrict__ cb, float* __restrict__ maxbuf) {
    const int bid = blockIdx.x, t = threadIdx.x;
    const float* src = bid < 2048 ? x : cb;
    const size_t base = bid < 2048 ? (size_t)bid * 4096 : (size_t)(bid - 2048) * 4096;
    float m = 0.f;
    #pragma unroll
    for (int i = 0; i < 4; ++i) {
        const float4 v = *(const float4*)(src + base + ((size_t)i * 256 + t) * 4);
        m = fmaxf(m, fmaxf(fmaxf(fabsf(v.x), fabsf(v.y)), fmaxf(fabsf(v.z), fabsf(v.w))));
    }
    #pragma unroll
    for (int off = 32; off; off >>= 1) m = fmaxf(m, __shfl_down(m, off));
    __shared__ float ps[4];
    if ((t & 63) == 0) ps[t >> 6] = m;
    __syncthreads();
    if (t == 0) maxbuf[bid] = fmaxf(fmaxf(ps[0], ps[1]), fmaxf(ps[2], ps[3]));
}

// ---------------- final scales + zero accumulators ----------------
__global__ void kscale(const float* __restrict__ maxbuf, float* __restrict__ scl,
                       float* __restrict__ counts, float* __restrict__ loss_arr,
                       unsigned* __restrict__ rcnt) {
    const int t = threadIdx.x;
    float mx = 0.f, me = 0.f;
    for (int i = t; i < 2048; i += 256) mx = fmaxf(mx, maxbuf[i]);
    for (int i = 2048 + t; i < 2560; i += 256) me = fmaxf(me, maxbuf[i]);
    #pragma unroll
    for (int off = 32; off; off >>= 1) {
        mx = fmaxf(mx, __shfl_down(mx, off));
        me = fmaxf(me, __shfl_down(me, off));
    }
    __shared__ float px[4], pe[4];
    if ((t & 63) == 0) { px[t >> 6] = mx; pe[t >> 6] = me; }
    __syncthreads();
    if (t == 0) {
        const float Sx = fmaxf(fmaxf(px[0], px[1]), fmaxf(px[2], px[3])) * (16384.f / 16320.f) + 1e-20f;
        const float Se = fmaxf(fmaxf(pe[0], pe[1]), fmaxf(pe[2], pe[3])) * (16384.f / 16320.f) + 1e-20f;
        scl[0] = Sx; scl[1] = Se; scl[2] = Sx * Se / 268435456.f;
        *rcnt = 0u;
    }
    for (int i = t; i < K_CODES; i += 256) counts[i] = 0.f;
    loss_arr[t] = 0.f;
}

// ---------------- encode cb (blocks 0-2047, + cnorm) and x (2048-4095, transpose) ----------------
__global__ __launch_bounds__(256)
void kprep(const float* __restrict__ cb, const float* __restrict__ x,
           signed char* __restrict__ Ah, signed char* __restrict__ Al,
           signed char* __restrict__ Bh, signed char* __restrict__ Bl,
           float* __restrict__ cnorm, const float* __restrict__ scl) {
    const int bid = blockIdx.x;
    const int t = threadIdx.x;
    if (bid < 2048) {
        const float inve = 16384.f / scl[1];
        const size_t i4 = ((size_t)bid * 256 + t) * 4;
        const float4 v = *(const float4*)(cb + i4);
        signed char h0, h1, h2, h3, l0, l1, l2, l3;
        enc8(v.x, inve, h0, l0); enc8(v.y, inve, h1, l1);
        enc8(v.z, inve, h2, l2); enc8(v.w, inve, h3, l3);
        *(char4*)(Bh + i4) = make_char4(h0, h1, h2, h3);
        *(char4*)(Bl + i4) = make_char4(l0, l1, l2, l3);
        float s = v.x * v.x + v.y * v.y + v.z * v.z + v.w * v.w;
        #pragma unroll
        for (int off = 32; off; off >>= 1) s += __shfl_down(s, off);
        if ((t & 63) == 0) cnorm[i4 >> 8] = s;
    } else {
        const float invx = 16384.f / scl[0];
        __shared__ float xt[64][65];
        const int xb_id = bid - 2048;       // 8 b * 4 ct * 64 st = 2048
        const int st = xb_id & 63;
        const int ct = (xb_id >> 6) & 3;
        const int b  = xb_id >> 8;
        const float* xb = x + ((size_t)b * C_DIM + ct * 64) * 4096 + st * 64;
        {
            const int s_l = t & 63, c0 = t >> 6;
            #pragma unroll
            for (int cc = 0; cc < 16; ++cc) {
                int c_l = cc * 4 + c0;
                xt[c_l][s_l] = xb[(size_t)c_l * 4096 + s_l];
            }
        }
        __syncthreads();
        const int c2 = (t & 31) * 2;
        const int s0 = t >> 5;
        #pragma unroll
        for (int ww = 0; ww < 8; ++ww) {
            int s_o = ww * 8 + s0;
            signed char h0, l0, h1, l1;
            enc8(xt[c2][s_o], invx, h0, l0);
            enc8(xt[c2 + 1][s_o], invx, h1, l1);
            size_t off = ((size_t)(b * 4096 + st * 64 + s_o)) * C_DIM + ct * 64 + c2;
            *(char2*)(Ah + off) = make_char2(h0, h1);
            *(char2*)(Al + off) = make_char2(l0, l1);
        }
    }
}

// ---------------- i8 MFMA distance GEMM + per-row top-2 argmin ----------------
// 128x256 tile, 8 waves (2Mx4N), per-wave 64x64 (acc[4][4]).
// BK=64 i8; fully-unrolled 12 K-tiles: 0-3 (h,h), <<7, 4-7 (h,l), 8-11 (l,h).
// u32 truncated-key epilogue: key = ((v >> 10) << 8) | local_code.
// Truncation (2^10 units ~ 0.025 dist) only affects near-ties, which are
// flagged (trunc_gap <= 2 covers every true gap < 0.05) and pair-rescued
// exactly in fp32.
__global__ __launch_bounds__(512, 4)
void kargmin_i8(const signed char* __restrict__ Ah, const signed char* __restrict__ Al,
                const signed char* __restrict__ Bh, const signed char* __restrict__ Bl,
                const float* __restrict__ cnorm, const float* __restrict__ scl,
                uint2* __restrict__ wsmin) {
    __shared__ unsigned char As[2][128 * 64];   // 8KB x2
    __shared__ unsigned char Bs[2][256 * 64];   // 16KB x2

    const int t = threadIdx.x;
    const int lane = t & 63;
    const int wid = t >> 6;
    const int xcd = blockIdx.x & 7;
    const int ii = blockIdx.x >> 3;              // 0..1023 within XCD
    const int ntile = xcd * 4 + (ii & 3);        // 0..31
    const int mtile = ii >> 2;                   // 0..255
    const int m0 = mtile * 128;
    const int n0 = ntile * 256;
    const int wr = wid >> 2;                     // 0..1
    const int wc = wid & 3;                      // 0..3
    const int wm = wr * 64;
    const int wn = wc * 64;
    const int lm = lane & 15;
    const int lh = lane >> 4;

    i32x4 acc[4][4];
    #pragma unroll
    for (int i = 0; i < 4; ++i)
        #pragma unroll
        for (int j = 0; j < 4; ++j) acc[i][j] = (i32x4){0, 0, 0, 0};

    // staging: rows of 64B = 4 slots of 16B; swizzle slot ^= (row&3)^((row>>2)&3)
    const int sAr = t >> 2;          // A row 0..127 (B rows sAr and 128+sAr, same swizzle)
    const int ssl = t & 3;
    const int gsA = ssl ^ (sAr & 3) ^ ((sAr >> 2) & 3);
    const size_t thr = (size_t)sAr * 256 + (size_t)gsA * 16;

    const signed char* pA0 = Ah + (size_t)m0 * 256 + thr;   // segs 0,1
    const signed char* pA1 = Al + (size_t)m0 * 256 + thr;   // seg 2
    const signed char* pB0 = Bh + (size_t)n0 * 256 + thr;   // segs 0,2
    const signed char* pB1 = Bl + (size_t)n0 * 256 + thr;   // seg 1

#define STAGE(PA, PB, KOFF, BUF) do { \
        GLDS16((PA) + (KOFF), &As[BUF][t * 16]); \
        GLDS16((PB) + (KOFF), &Bs[BUF][t * 16]); \
        GLDS16((PB) + 32768 + (KOFF), &Bs[BUF][(512 + t) * 16]); \
    } while (0)

    const int rboff = (lh ^ (lm & 3) ^ ((lm >> 2) & 3)) * 16;

#define TILE(CUR, PF, FOLD) do { \
        PF; \
        i32x4 a_[4], b_[4]; \
        _Pragma("unroll") \
        for (int j = 0; j < 4; ++j) \
            b_[j] = *(const i32x4*)&Bs[CUR][(wn + j * 16 + lm) * 64 + rboff]; \
        _Pragma("unroll") \
        for (int i = 0; i < 4; ++i) \
            a_[i] = *(const i32x4*)&As[CUR][(wm + i * 16 + lm) * 64 + rboff]; \
        _Pragma("unroll") \
        for (int i = 0; i < 4; ++i) \
            _Pragma("unroll") \
            for (int j = 0; j < 4; ++j) \
                acc[i][j] = __builtin_amdgcn_mfma_i32_16x16x64_i8(a_[i], b_[j], acc[i][j], 0, 0, 0); \
        FOLD; \
        __syncthreads(); \
    } while (0)

#define FOLDACC \
        _Pragma("unroll") \
        for (int i = 0; i < 4; ++i) \
            _Pragma("unroll") \
            for (int j = 0; j < 4; ++j) \
                acc[i][j] = acc[i][j] << 7

    STAGE(pA0, pB0, 0, 0);
    __syncthreads();
    TILE(0, STAGE(pA0, pB0, 64, 1), (void)0);
    TILE(1, STAGE(pA0, pB0, 128, 0), (void)0);
    TILE(0, STAGE(pA0, pB0, 192, 1), (void)0);
    TILE(1, STAGE(pA0, pB1, 0, 0), FOLDACC);     // H done -> acc = 128*H
    TILE(0, STAGE(pA0, pB1, 64, 1), (void)0);
    TILE(1, STAGE(pA0, pB1, 128, 0), (void)0);
    TILE(0, STAGE(pA0, pB1, 192, 1), (void)0);
    TILE(1, STAGE(pA1, pB0, 0, 0), (void)0);
    TILE(0, STAGE(pA1, pB0, 64, 1), (void)0);
    TILE(1, STAGE(pA1, pB0, 128, 0), (void)0);
    TILE(0, STAGE(pA1, pB0, 192, 1), (void)0);
    TILE(1, (void)0, (void)0);
#undef TILE
#undef STAGE
#undef FOLDACC

    // u32 truncated-key epilogue: v = bias + cni - acc (>=0); key=(v>>10)<<8|code
    const float invu = 1.f / (256.f * scl[2]);
    int cni[4];
    #pragma unroll
    for (int j = 0; j < 4; ++j)
        cni[j] = (int)rintf(cnorm[n0 + wn + j * 16 + lm] * invu) + 0x20000000;

    u32* redbuf = (u32*)&As[0][0];   // 128 rows x 4 wc x 2 u32 = 4KB
    #pragma unroll
    for (int i = 0; i < 4; ++i) {
        u32 p1[4], p2[4];
        #pragma unroll
        for (int r = 0; r < 4; ++r) {
            u32 b1 = ~0u, b2 = ~0u;
            #pragma unroll
            for (int j = 0; j < 4; ++j) {
                const u32 v = (u32)(cni[j] - acc[i][j][r]);
                const u32 key = ((v >> 10) << 8) | (u32)(wn + j * 16 + lm);
                if (key < b1) { b2 = b1; b1 = key; }
                else if (key < b2) b2 = key;
            }
            p1[r] = b1; p2[r] = b2;
        }
        #pragma unroll
        for (int off = 1; off < 16; off <<= 1) {
            #pragma unroll
            for (int r = 0; r < 4; ++r) {
                const u32 o1 = __shfl_xor(p1[r], off);
                const u32 o2 = __shfl_xor(p2[r], off);
                const u32 lo = min(p1[r], o1);
                const u32 hi = max(p1[r], o1);
                p1[r] = lo;
                p2[r] = min(hi, min(p2[r], o2));
            }
        }
        if (lm == 0) {
            #pragma unroll
            for (int r = 0; r < 4; ++r) {
                const int rl = wm + i * 16 + lh * 4 + r;   // 0..127
                redbuf[rl * 8 + wc * 2 + 0] = p1[r];
                redbuf[rl * 8 + wc * 2 + 1] = p2[r];
            }
        }
    }
    __syncthreads();
    if (t < 128) {
        u32 m1 = ~0u, m2 = ~0u;
        #pragma unroll
        for (int w = 0; w < 4; ++w) {
            const u32 a1 = redbuf[t * 8 + w * 2 + 0];
            const u32 a2 = redbuf[t * 8 + w * 2 + 1];
            const u32 lo = min(m1, a1);
            const u32 hi = max(m1, a1);
            m1 = lo;
            m2 = min(hi, min(m2, a2));
        }
        wsmin[(size_t)(m0 + t) * 32 + ntile] = make_uint2(m1, m2);
    }
}

// ---------------- combine per-ntile mins; histogram; flag near-ties ----------------
__global__ void kcombine(const uint2* __restrict__ wsmin, float* __restrict__ idxf,
                         unsigned* __restrict__ rcnt, unsigned* __restrict__ rrows,
                         uint2* __restrict__ rpair, float* __restrict__ counts) {
    const int row = blockIdx.x * 256 + threadIdx.x;
    const uint2* p = wsmin + (size_t)row * 32;
    u32 m1 = ~0u, m2 = ~0u;
    int nt1 = 0, nt2 = 0;
    for (int nt = 0; nt < 32; ++nt) {
        const uint2 c = p[nt];
        if (c.x < m1) { m2 = m1; nt2 = nt1; m1 = c.x; nt1 = nt; }
        else if (c.x < m2) { m2 = c.x; nt2 = nt; }
        if (c.y < m2) { m2 = c.y; nt2 = nt; }
    }
    const int k = nt1 * 256 + (int)(m1 & 255u);
    idxf[row] = (float)k;
    atomicAdd(&counts[k], 1.0f);
    if ((m2 >> 8) - (m1 >> 8) <= RESC_KEYGAP) {
        unsigned slot = atomicAdd(rcnt, 1u);
        if (slot < RESC_CAP) {
            rrows[slot] = (unsigned)row;
            rpair[slot] = make_uint2((unsigned)k, (unsigned)(nt2 * 256 + (int)(m2 & 255u)));
        }
    }
}

// ---------------- exact fp32 pair re-score (wave per flagged row) ----------------
__global__ __launch_bounds__(256)
void krescue2(const float* __restrict__ x, const float* __restrict__ cb,
              const float* __restrict__ cnorm, const unsigned* __restrict__ rcnt,
              const unsigned* __restrict__ rrows, const uint2* __restrict__ rpair,
              float* __restrict__ idxf, float* __restrict__ counts) {
    const int lane = threadIdx.x & 63;
    const int wv = threadIdx.x >> 6;
    unsigned cnt = *rcnt; if (cnt > RESC_CAP) cnt = RESC_CAP;
    for (unsigned i = blockIdx.x * 4 + wv; i < cnt; i += gridDim.x * 4) {
        const int row = (int)rrows[i];
        const uint2 kk = rpair[i];
        const int b = row >> 12, s = row & 4095;
        float d1 = 0.f, d2 = 0.f;
        #pragma unroll
        for (int q = 0; q < 4; ++q) {
            const int c = lane + q * 64;
            const float xv = x[((size_t)(b * 256 + c)) * 4096 + s];
            d1 = fmaf(xv, cb[(size_t)kk.x * 256 + c], d1);
            d2 = fmaf(xv, cb[(size_t)kk.y * 256 + c], d2);
        }
        #pragma unroll
        for (int off = 32; off; off >>= 1) {
            d1 += __shfl_down(d1, off);
            d2 += __shfl_down(d2, off);
        }
        if (lane == 0) {
            const float dist1 = fmaf(-2.f, d1, cnorm[kk.x]);
            const float dist2 = fmaf(-2.f, d2, cnorm[kk.y]);
            const u64 p1 = ((u64)fkey(dist1) << 32) | kk.x;
            const u64 p2 = ((u64)fkey(dist2) << 32) | kk.y;
            const int knew = (int)(unsigned)((p1 < p2 ? p1 : p2) & 0xffffffffu);
            const int kold = (int)kk.x;
            if (knew != kold) {
                atomicAdd(&counts[kold], -1.0f);
                atomicAdd(&counts[knew], 1.0f);
                idxf[row] = (float)knew;
            }
        }
    }
}

// ---------------- CSR build: scan / scatter ----------------
__global__ void kscan(const float* __restrict__ counts, unsigned* __restrict__ off,
                      unsigned* __restrict__ cursor) {
    __shared__ unsigned part[256];
    const int t = threadIdx.x;
    unsigned local[32];
    unsigned s = 0;
    #pragma unroll
    for (int i = 0; i < 32; ++i) { local[i] = s; s += (unsigned)counts[t * 32 + i]; }
    part[t] = s;
    __syncthreads();
    if (t == 0) {
        unsigned run = 0;
        for (int i = 0; i < 256; ++i) { unsigned v = part[i]; part[i] = run; run += v; }
    }
    __syncthreads();
    const unsigned base = part[t];
    #pragma unroll
    for (int i = 0; i < 32; ++i) {
        unsigned o = base + local[i];
        off[t * 32 + i] = o;
        cursor[t * 32 + i] = o;
    }
}

__global__ void kscatter(const float* __restrict__ idxf, unsigned* __restrict__ cursor,
                         unsigned* __restrict__ rowlist) {
    const int n = blockIdx.x * 256 + threadIdx.x;
    const int k = (int)idxf[n];
    unsigned pos = atomicAdd(&cursor[k], 1u);
    rowlist[pos] = (unsigned)n;
}

// ---------------- dw = segment_sum(x) via CSR, exact-int from i8 planes ----------------
__global__ void kdw(const signed char* __restrict__ Ah, const signed char* __restrict__ Al,
                    const float* __restrict__ counts, const unsigned* __restrict__ off,
                    const unsigned* __restrict__ rowlist, const float* __restrict__ scl,
                    float* __restrict__ dwout) {
    const int k = blockIdx.x;
    const int lane = threadIdx.x;   // 64
    const int cnt = (int)counts[k];
    const unsigned base = off[k];
    int ax = 0, ay = 0, az = 0, aw = 0;
    for (int i = 0; i < cnt; ++i) {
        const unsigned row = rowlist[base + i];
        const char4 h = *(const char4*)(Ah + (size_t)row * C_DIM + lane * 4);
        const char4 l = *(const char4*)(Al + (size_t)row * C_DIM + lane * 4);
        ax += h.x * 128 + l.x;
        ay += h.y * 128 + l.y;
        az += h.z * 128 + l.z;
        aw += h.w * 128 + l.w;
    }
    const float sxf = scl[0] * (1.f / 16384.f);
    float4 o;
    o.x = (float)ax * sxf; o.y = (float)ay * sxf;
    o.z = (float)az * sxf; o.w = (float)aw * sxf;
    *(float4*)(dwout + (size_t)k * C_DIM + lane * 4) = o;
}

// ---------------- quantize (gather-transpose) + e_loss ----------------
__global__ __launch_bounds__(256)
void kquant2(const float* __restrict__ x, const float* __restrict__ cb,
             const float* __restrict__ idxf, float* __restrict__ qout,
             float* __restrict__ loss_arr) {
    __shared__ int ki[64];
    __shared__ float cbt[64][257];
    const int t = threadIdx.x;
    const int bid = blockIdx.x;
    const int chunk = bid & 63;
    const int b = bid >> 6;
    const int s0 = chunk * 64;
    if (t < 64) ki[t] = (int)idxf[b * 4096 + s0 + t];
    __syncthreads();
    {
        const int lane = t & 63;
        const int rr = t >> 6;
        #pragma unroll
        for (int p = 0; p < 16; ++p) {
            const int r = p * 4 + rr;
            const float4 v = *(const float4*)(cb + (size_t)ki[r] * C_DIM + lane * 4);
            cbt[r][lane * 4 + 0] = v.x;
            cbt[r][lane * 4 + 1] = v.y;
            cbt[r][lane * 4 + 2] = v.z;
            cbt[r][lane * 4 + 3] = v.w;
        }
    }
    __syncthreads();
    const int sg = t & 15;
    const int c0 = t >> 4;
    float lsum = 0.f;
    #pragma unroll
    for (int cc = 0; cc < 16; ++cc) {
        const int c = cc * 16 + c0;
        const size_t go = ((size_t)b * C_DIM + c) * 4096 + s0 + sg * 4;
        const float4 xv = *(const float4*)(x + go);
        float qx = cbt[sg * 4 + 0][c];
        float qy = cbt[sg * 4 + 1][c];
        float qz = cbt[sg * 4 + 2][c];
        float qw = cbt[sg * 4 + 3][c];
        float4 st;
        st.x = xv.x + (qx - xv.x);
        st.y = xv.y + (qy - xv.y);
        st.z = xv.z + (qz - xv.z);
        st.w = xv.w + (qw - xv.w);
        *(float4*)(qout + go) = st;
        float dx = qx - xv.x, dy = qy - xv.y, dz = qz - xv.z, dw_ = qw - xv.w;
        lsum += dx * dx + dy * dy + dz * dz + dw_ * dw_;
    }
    #pragma unroll
    for (int off = 32; off; off >>= 1) lsum += __shfl_down(lsum, off);
    __shared__ float ps[4];
    if ((t & 63) == 0) ps[t >> 6] = lsum;
    __syncthreads();
    if (t == 0) atomicAdd(&loss_arr[bid & 255], ps[0] + ps[1] + ps[2] + ps[3]);
}

// ---------------- EMA finalize + stats (fused; block K_CODES does stats) ----------------
__global__ void kfinal2(const float* __restrict__ ema_c, const float* __restrict__ ema_w,
                        const float* __restrict__ counts, float* __restrict__ dw,
                        float* __restrict__ ncb, float* __restrict__ ncnt_out,
                        const float* __restrict__ loss_arr, float* __restrict__ out) {
    const int k = blockIdx.x;
    const int t = threadIdx.x;
    if (k < K_CODES) {
        const float ncnt = (DECAYF * ema_c[k] + (1.f - DECAYF) * counts[k] + EPSF)
                           / (8.f + (float)K_CODES * EPSF) * 8.f;
        const size_t o = (size_t)k * C_DIM + t;
        const float nwv = DECAYF * ema_w[o] + (1.f - DECAYF) * dw[o];
        dw[o]  = nwv;
        ncb[o] = nwv / ncnt;
        if (t == 0) ncnt_out[k] = ncnt;
    } else {
        float nz = 0.f, s = 0.f;
        for (int kk = t; kk < K_CODES; kk += 256) {
            float cnt = counts[kk];
            if (cnt != 0.f) nz += 1.f;
            float p = cnt * (1.f / 32768.f);
            s += p * logf(p + 1e-10f);
        }
        float ls = loss_arr[t];
        #pragma unroll
        for (int off = 32; off; off >>= 1) {
            s  += __shfl_down(s, off);
            nz += __shfl_down(nz, off);
            ls += __shfl_down(ls, off);
        }
        __shared__ float ss[4], zz[4], ll[4];
        const int wid = t >> 6, lane = t & 63;
        if (lane == 0) { ss[wid] = s; zz[wid] = nz; ll[wid] = ls; }
        __syncthreads();
        if (t == 0) {
            float st = ss[0] + ss[1] + ss[2] + ss[3];
            float zt = zz[0] + zz[1] + zz[2] + zz[3];
            float lt = ll[0] + ll[1] + ll[2] + ll[3];
            out[OFF_ELOSS] = COMMITF * lt / 8388608.f;
            out[OFF_PERP]  = expf(-st);
            out[OFF_UNIQ]  = zt;
        }
    }
}

// ======= fallback fp32 path (used only if ws too small) =======
__global__ void knorm(const float* __restrict__ cb, float* __restrict__ cnorm) {
    const int wid  = threadIdx.x >> 6;
    const int lane = threadIdx.x & 63;
    const int row  = blockIdx.x * 4 + wid;
    const float4 v = *(const float4*)(cb + (size_t)row * C_DIM + lane * 4);
    float s = v.x * v.x + v.y * v.y + v.z * v.z + v.w * v.w;
    #pragma unroll
    for (int off = 32; off; off >>= 1) s += __shfl_down(s, off);
    if (lane == 0) cnorm[row] = s;
}

__launch_bounds__(256, 1)
__global__ void kargmin_fp32(const float* __restrict__ x, const float* __restrict__ cb,
                             const float* __restrict__ cnorm, float* __restrict__ idxf) {
    __shared__ float xs[64][256];
    __shared__ float es[64][256];
    const int t  = threadIdx.x;
    const int n0 = blockIdx.x * 64;
    const int b  = n0 >> 12;
    const int s0 = n0 & 4095;
    {
        const int r  = t & 63;
        const int c0 = t >> 6;
        const float* xb = x + (size_t)b * C_DIM * 4096 + s0 + r;
        const int sw = SWZ(r);
        #pragma unroll 8
        for (int cc = 0; cc < 64; ++cc) {
            int c = cc * 4 + c0;
            xs[r][c ^ sw] = xb[(size_t)c * 4096];
        }
    }
    const int mg  = t >> 4;
    const int ng  = t & 15;
    const int m0  = mg * 4;
    const int nn0 = ng * 4;
    const int swm = SWZ(m0);
    const int swn = SWZ(nn0);
    float minv[4] = {1e30f, 1e30f, 1e30f, 1e30f};
    int   mini[4] = {0, 0, 0, 0};
    for (int k0 = 0; k0 < K_CODES; k0 += 64) {
        __syncthreads();
        {
            const int lane = t & 63;
            const int cw   = t >> 6;
            #pragma unroll
            for (int p = 0; p < 16; ++p) {
                int code = p * 4 + cw;
                float4 v = *(const float4*)(cb + (size_t)(k0 + code) * C_DIM + lane * 4);
                *(float4*)&es[code][(lane * 4) ^ SWZ(code)] = v;
            }
        }
        float cn[4];
        #pragma unroll
        for (int j = 0; j < 4; ++j) cn[j] = cnorm[k0 + nn0 + j];
        __syncthreads();
        float acc[4][4];
        #pragma unroll
        for (int i = 0; i < 4; ++i)
            #pragma unroll
            for (int j = 0; j < 4; ++j) acc[i][j] = 0.f;
        #pragma unroll 4
        for (int c = 0; c < C_DIM; c += 4) {
            float4 xa[4], eb[4];
            #pragma unroll
            for (int i = 0; i < 4; ++i) xa[i] = *(const float4*)&xs[m0 + i][c ^ swm];
            #pragma unroll
            for (int j = 0; j < 4; ++j) eb[j] = *(const float4*)&es[nn0 + j][c ^ swn];
            #pragma unroll
            for (int i = 0; i < 4; ++i)
                #pragma unroll
                for (int j = 0; j < 4; ++j)
                    acc[i][j] += xa[i].x * eb[j].x + xa[i].y * eb[j].y +
                                 xa[i].z * eb[j].z + xa[i].w * eb[j].w;
        }
        #pragma unroll
        for (int j = 0; j < 4; ++j) {
            const int kg = k0 + nn0 + j;
            #pragma unroll
            for (int i = 0; i < 4; ++i) {
                float dist = fmaf(-2.f, acc[i][j], cn[j]);
                if (dist < minv[i]) { minv[i] = dist; mini[i] = kg; }
            }
        }
    }
    #pragma unroll
    for (int off = 1; off < 16; off <<= 1) {
        #pragma unroll
        for (int i = 0; i < 4; ++i) {
            float ov = __shfl_xor(minv[i], off);
            int   oi = __shfl_xor(mini[i], off);
            if (ov < minv[i] || (ov == minv[i] && oi < mini[i])) { minv[i] = ov; mini[i] = oi; }
        }
    }
    if (ng == 0) {
        #pragma unroll
        for (int i = 0; i < 4; ++i) idxf[n0 + m0 + i] = (float)mini[i];
    }
}

__global__ void kquant_legacy(const float* __restrict__ x, const float* __restrict__ cb,
                              const float* __restrict__ idxf, float* __restrict__ qout,
                              float* __restrict__ dw, float* __restrict__ counts,
                              float* __restrict__ loss_arr) {
    const int t   = threadIdx.x;
    const int bid = blockIdx.x;
    const int sc  = bid & 15;
    const int c   = (bid >> 4) & 255;
    const int b   = bid >> 12;
    const int s   = sc * 256 + t;
    const int n   = b * 4096 + s;
    const int k   = (int)idxf[n];
    const size_t xoff = ((size_t)b * C_DIM + c) * 4096 + s;
    const float xv = x[xoff];
    const float q  = cb[(size_t)k * C_DIM + c];
    qout[xoff] = xv + (q - xv);
    atomicAdd(&dw[(size_t)k * C_DIM + c], xv);
    if (c == 0) atomicAdd(&counts[k], 1.0f);
    float d = q - xv;
    float p = d * d;
    #pragma unroll
    for (int off = 32; off; off >>= 1) p += __shfl_down(p, off);
    __shared__ float ps[4];
    if ((t & 63) == 0) ps[t >> 6] = p;
    __syncthreads();
    if (t == 0) atomicAdd(&loss_arr[bid & 255], ps[0] + ps[1] + ps[2] + ps[3]);
}

__global__ void kstats_legacy(const float* __restrict__ counts, const float* __restrict__ loss_arr,
                              float* __restrict__ out) {
    const int t = threadIdx.x;
    float nz = 0.f, s = 0.f;
    for (int k = t; k < K_CODES; k += 256) {
        float cnt = counts[k];
        if (cnt != 0.f) nz += 1.f;
        float p = cnt * (1.f / 32768.f);
        s += p * logf(p + 1e-10f);
    }
    float ls = loss_arr[t];
    #pragma unroll
    for (int off = 32; off; off >>= 1) {
        s  += __shfl_down(s, off);
        nz += __shfl_down(nz, off);
        ls += __shfl_down(ls, off);
    }
    __shared__ float ss[4], zz[4], ll[4];
    const int wid = t >> 6, lane = t & 63;
    if (lane == 0) { ss[wid] = s; zz[wid] = nz; ll[wid] = ls; }
    __syncthreads();
    if (t == 0) {
        out[OFF_ELOSS] = COMMITF * (ll[0] + ll[1] + ll[2] + ll[3]) / 8388608.f;
        out[OFF_PERP]  = expf(-(ss[0] + ss[1] + ss[2] + ss[3]));
        out[OFF_UNIQ]  = zz[0] + zz[1] + zz[2] + zz[3];
    }
}

__global__ void kfinal_legacy(const float* __restrict__ ema_c, const float* __restrict__ ema_w,
                              float* __restrict__ counts, float* __restrict__ dw,
                              float* __restrict__ ncb) {
    const int k = blockIdx.x;
    const int c = threadIdx.x;
    const float cnt  = counts[k];
    const float ncnt = (DECAYF * ema_c[k] + (1.f - DECAYF) * cnt + EPSF)
                       / (8.f + (float)K_CODES * EPSF) * 8.f;
    const size_t o = (size_t)k * C_DIM + c;
    const float nw = DECAYF * ema_w[o] + (1.f - DECAYF) * dw[o];
    __syncthreads();
    dw[o]  = nw;
    ncb[o] = nw / ncnt;
    if (c == 0) counts[k] = ncnt;
}

extern "C" void kernel_launch(void* const* d_in, const int* in_sizes, int n_in,
                              void* d_out, int out_size, void* d_ws, size_t ws_size,
                              hipStream_t stream) {
    const float* x     = (const float*)d_in[0];
    const float* cb    = (const float*)d_in[1];
    const float* ema_c = (const float*)d_in[2];
    const float* ema_w = (const float*)d_in[3];
    float* out = (float*)d_out;

    float* qout = out + OFF_QUANT;
    float* ncb  = out + OFF_NCB;
    float* ncnt = out + OFF_NCNT;
    float* nw   = out + OFF_NW;
    float* idxf = out + OFF_IDX;

    const size_t szA = (size_t)N_ROWS * C_DIM;    // 8388608 bytes per plane
    const size_t szB = (size_t)K_CODES * C_DIM;   // 2097152
    const size_t fcount = 8192 + 256 + 8192 + 4 + 2560;
    const size_t need = 2 * szA + 2 * szB + fcount * 4
                      + RESC_CAP * 8 + RESC_CAP * 4 + 4 + 8192 * 4 * 2 + 32768 * 4 + 64;
    const bool use_i8 = ws_size >= need;

    if (use_i8) {
        signed char* Ah = (signed char*)d_ws;
        signed char* Al = Ah + szA;
        signed char* Bh = Al + szA;
        signed char* Bl = Bh + szB;
        float* fbase      = (float*)(Bl + szB);
        float* cnorm      = fbase;
        float* loss_arr   = fbase + 8192;
        float* counts_raw = fbase + 8448;
        float* scl        = fbase + 16640;
        float* maxbuf     = fbase + 16644;
        uint2* rpair      = (uint2*)(fbase + fcount);
        unsigned* rrows   = (unsigned*)(rpair + RESC_CAP);
        unsigned* rcnt    = rrows + RESC_CAP;
        unsigned* off     = rcnt + 1;
        unsigned* cursor  = off + K_CODES;
        unsigned* rowlist = cursor + K_CODES;
        uint2* wsmin = (uint2*)(out + OFF_QUANT);   // 8.4 MB, consumed before kquant2 writes qout

        kmax<<<2560, 256, 0, stream>>>(x, cb, maxbuf);
        kscale<<<1, 256, 0, stream>>>(maxbuf, scl, counts_raw, loss_arr, rcnt);
        kprep<<<4096, 256, 0, stream>>>(cb, x, Ah, Al, Bh, Bl, cnorm, scl);
        kargmin_i8<<<8192, 512, 0, stream>>>(Ah, Al, Bh, Bl, cnorm, scl, wsmin);
        kcombine<<<N_ROWS / 256, 256, 0, stream>>>(wsmin, idxf, rcnt, rrows, rpair, counts_raw);
        krescue2<<<256, 256, 0, stream>>>(x, cb, cnorm, rcnt, rrows, rpair, idxf, counts_raw);
        kscan<<<1, 256, 0, stream>>>(counts_raw, off, cursor);
        kscatter<<<N_ROWS / 256, 256, 0, stream>>>(idxf, cursor, rowlist);
        kdw<<<K_CODES, 64, 0, stream>>>(Ah, Al, counts_raw, off, rowlist, scl, nw);
        kquant2<<<512, 256, 0, stream>>>(x, cb, idxf, qout, loss_arr);
        kfinal2<<<K_CODES + 1, C_DIM, 0, stream>>>(ema_c, ema_w, counts_raw, nw, ncb, ncnt,
                                                   loss_arr, out);
    } else {
        float* cnorm = (float*)d_ws;
        float* loss_arr = cnorm + K_CODES;
        hipMemsetAsync(ncnt, 0, K_CODES * sizeof(float), stream);
        hipMemsetAsync(nw, 0, (size_t)K_CODES * C_DIM * sizeof(float), stream);
        hipMemsetAsync(loss_arr, 0, 256 * sizeof(float), stream);
        knorm<<<K_CODES / 4, 256, 0, stream>>>(cb, cnorm);
        kargmin_fp32<<<N_ROWS / 64, 256, 0, stream>>>(x, cb, cnorm, idxf);
        kquant_legacy<<<32768, 256, 0, stream>>>(x, cb, idxf, qout, nw, ncnt, loss_arr);
        kstats_legacy<<<1, 256, 0, stream>>>(ncnt, loss_arr, out);
        kfinal_legacy<<<K_CODES, C_DIM, 0, stream>>>(ema_c, ema_w, ncnt, nw, ncb);
    }
}

// Round 17
// 463.801 us; speedup vs baseline: 1.3576x; 1.2330x over previous
//
#include <hip/hip_runtime.h>
#include <hip/hip_bf16.h>
#include <stdint.h>

#define N_ROWS 32768
#define K_CODES 8192
#define C_DIM 256
#define DECAYF 0.95f
#define COMMITF 0.25f
#define EPSF 1e-5f
#define RESC_KEYGAP 2u
#define RESC_CAP 16384

// d_out layout (floats), reference return order
#define OFF_QUANT 0
#define OFF_ELOSS 8388608
#define OFF_PERP  8388609
#define OFF_UNIQ  8388610
#define OFF_NCB   8388611
#define OFF_NCNT  10485763
#define OFF_NW    10493955
#define OFF_IDX   12591107

typedef float f32x4 __attribute__((ext_vector_type(4)));
typedef int i32x4 __attribute__((ext_vector_type(4)));
typedef unsigned long long u64;
typedef unsigned int u32;

#define SWZ(r) ((((r) >> 2) & 7) << 2)

#if defined(__has_builtin)
#if __has_builtin(__builtin_amdgcn_global_load_lds)
#define HAVE_GLDS 1
#endif
#endif
#ifdef HAVE_GLDS
#define GLDS16(g, l) __builtin_amdgcn_global_load_lds( \
    (const __attribute__((address_space(1))) void*)(uintptr_t)(g), \
    (__attribute__((address_space(3))) void*)(uint32_t)(uintptr_t)(l), 16, 0, 0)
#else
#define GLDS16(g, l) do { *(float4*)(l) = *(const float4*)(g); } while (0)
#endif

__device__ __forceinline__ uint32_t fkey(float f) {
    uint32_t b = __float_as_uint(f);
    return b ^ ((uint32_t)((int32_t)b >> 31) | 0x80000000u);
}
// 14-bit fixed-point -> two signed i8 (h*128 + l), l in [-64,63]
__device__ __forceinline__ void enc8(float v, float inv, signed char& h, signed char& l) {
    int q = __float2int_rn(v * inv);
    q = q > 16319 ? 16319 : (q < -16320 ? -16320 : q);
    int hh = (q + 64) >> 7;
    h = (signed char)hh;
    l = (signed char)(q - (hh << 7));
}

// ---------------- per-block absmax of x (blocks 0-2047) and cb (2048-2559) ----------------
__global__ __launch_bounds__(256)
void kmax(const float* __restrict__ x, const float* __restrict__ cb, float* __restrict__ maxbuf) {
    const int bid = blockIdx.x, t = threadIdx.x;
    const float* src = bid < 2048 ? x : cb;
    const size_t base = bid < 2048 ? (size_t)bid * 4096 : (size_t)(bid - 2048) * 4096;
    float m = 0.f;
    #pragma unroll
    for (int i = 0; i < 4; ++i) {
        const float4 v = *(const float4*)(src + base + ((size_t)i * 256 + t) * 4);
        m = fmaxf(m, fmaxf(fmaxf(fabsf(v.x), fabsf(v.y)), fmaxf(fabsf(v.z), fabsf(v.w))));
    }
    #pragma unroll
    for (int off = 32; off; off >>= 1) m = fmaxf(m, __shfl_down(m, off));
    __shared__ float ps[4];
    if ((t & 63) == 0) ps[t >> 6] = m;
    __syncthreads();
    if (t == 0) maxbuf[bid] = fmaxf(fmaxf(ps[0], ps[1]), fmaxf(ps[2], ps[3]));
}

// ---------------- final scales + zero accumulators ----------------
__global__ void kscale(const float* __restrict__ maxbuf, float* __restrict__ scl,
                       float* __restrict__ counts, float* __restrict__ loss_arr,
                       unsigned* __restrict__ rcnt) {
    const int t = threadIdx.x;
    float mx = 0.f, me = 0.f;
    for (int i = t; i < 2048; i += 256) mx = fmaxf(mx, maxbuf[i]);
    for (int i = 2048 + t; i < 2560; i += 256) me = fmaxf(me, maxbuf[i]);
    #pragma unroll
    for (int off = 32; off; off >>= 1) {
        mx = fmaxf(mx, __shfl_down(mx, off));
        me = fmaxf(me, __shfl_down(me, off));
    }
    __shared__ float px[4], pe[4];
    if ((t & 63) == 0) { px[t >> 6] = mx; pe[t >> 6] = me; }
    __syncthreads();
    if (t == 0) {
        const float Sx = fmaxf(fmaxf(px[0], px[1]), fmaxf(px[2], px[3])) * (16384.f / 16320.f) + 1e-20f;
        const float Se = fmaxf(fmaxf(pe[0], pe[1]), fmaxf(pe[2], pe[3])) * (16384.f / 16320.f) + 1e-20f;
        scl[0] = Sx; scl[1] = Se; scl[2] = Sx * Se / 268435456.f;
        *rcnt = 0u;
    }
    for (int i = t; i < K_CODES; i += 256) counts[i] = 0.f;
    loss_arr[t] = 0.f;
}

// ---------------- encode cb (blocks 0-2047, + cnorm) and x (2048-4095, transpose) ----------------
__global__ __launch_bounds__(256)
void kprep(const float* __restrict__ cb, const float* __restrict__ x,
           signed char* __restrict__ Ah, signed char* __restrict__ Al,
           signed char* __restrict__ Bh, signed char* __restrict__ Bl,
           float* __restrict__ cnorm, const float* __restrict__ scl) {
    const int bid = blockIdx.x;
    const int t = threadIdx.x;
    if (bid < 2048) {
        const float inve = 16384.f / scl[1];
        const size_t i4 = ((size_t)bid * 256 + t) * 4;
        const float4 v = *(const float4*)(cb + i4);
        signed char h0, h1, h2, h3, l0, l1, l2, l3;
        enc8(v.x, inve, h0, l0); enc8(v.y, inve, h1, l1);
        enc8(v.z, inve, h2, l2); enc8(v.w, inve, h3, l3);
        *(char4*)(Bh + i4) = make_char4(h0, h1, h2, h3);
        *(char4*)(Bl + i4) = make_char4(l0, l1, l2, l3);
        float s = v.x * v.x + v.y * v.y + v.z * v.z + v.w * v.w;
        #pragma unroll
        for (int off = 32; off; off >>= 1) s += __shfl_down(s, off);
        if ((t & 63) == 0) cnorm[i4 >> 8] = s;
    } else {
        const float invx = 16384.f / scl[0];
        __shared__ float xt[64][65];
        const int xb_id = bid - 2048;       // 8 b * 4 ct * 64 st = 2048
        const int st = xb_id & 63;
        const int ct = (xb_id >> 6) & 3;
        const int b  = xb_id >> 8;
        const float* xb = x + ((size_t)b * C_DIM + ct * 64) * 4096 + st * 64;
        {
            const int s_l = t & 63, c0 = t >> 6;
            #pragma unroll
            for (int cc = 0; cc < 16; ++cc) {
                int c_l = cc * 4 + c0;
                xt[c_l][s_l] = xb[(size_t)c_l * 4096 + s_l];
            }
        }
        __syncthreads();
        const int c2 = (t & 31) * 2;
        const int s0 = t >> 5;
        #pragma unroll
        for (int ww = 0; ww < 8; ++ww) {
            int s_o = ww * 8 + s0;
            signed char h0, l0, h1, l1;
            enc8(xt[c2][s_o], invx, h0, l0);
            enc8(xt[c2 + 1][s_o], invx, h1, l1);
            size_t off = ((size_t)(b * 4096 + st * 64 + s_o)) * C_DIM + ct * 64 + c2;
            *(char2*)(Ah + off) = make_char2(h0, h1);
            *(char2*)(Al + off) = make_char2(l0, l1);
        }
    }
}

// ---------------- i8 MFMA distance GEMM + per-row top-2 argmin ----------------
// 128x256 tile, 8 waves (2Mx4N), per-wave 64x64 (acc[4][4]).
// BK=64 i8; 12 K-tiles: 0-3 (h,h), <<7, 4-7 (h,l), 8-11 (l,h).
// DEPTH-2 pipeline: 3 LDS buffers (72KB, 2 blocks/CU); stage tile kt+2;
// tile-end = s_waitcnt vmcnt(3) + s_barrier (newest stage stays in flight;
// T4 counted-vmcnt -- never drain to 0 in the main loop).
__global__ __launch_bounds__(512, 4)
void kargmin_i8(const signed char* __restrict__ Ah, const signed char* __restrict__ Al,
                const signed char* __restrict__ Bh, const signed char* __restrict__ Bl,
                const float* __restrict__ cnorm, const float* __restrict__ scl,
                uint2* __restrict__ wsmin) {
    __shared__ unsigned char As[3][128 * 64];   // 8KB x3
    __shared__ unsigned char Bs[3][256 * 64];   // 16KB x3

    const int t = threadIdx.x;
    const int lane = t & 63;
    const int wid = t >> 6;
    const int xcd = blockIdx.x & 7;
    const int ii = blockIdx.x >> 3;              // 0..1023 within XCD
    const int ntile = xcd * 4 + (ii & 3);        // 0..31
    const int mtile = ii >> 2;                   // 0..255
    const int m0 = mtile * 128;
    const int n0 = ntile * 256;
    const int wr = wid >> 2;                     // 0..1
    const int wc = wid & 3;                      // 0..3
    const int wm = wr * 64;
    const int wn = wc * 64;
    const int lm = lane & 15;
    const int lh = lane >> 4;

    i32x4 acc[4][4];
    #pragma unroll
    for (int i = 0; i < 4; ++i)
        #pragma unroll
        for (int j = 0; j < 4; ++j) acc[i][j] = (i32x4){0, 0, 0, 0};

    // staging: rows of 64B = 4 slots of 16B; swizzle slot ^= (row&3)^((row>>2)&3)
    const int sAr = t >> 2;          // A row 0..127 (B rows sAr and 128+sAr, same swizzle)
    const int ssl = t & 3;
    const int gsA = ssl ^ (sAr & 3) ^ ((sAr >> 2) & 3);
    const size_t thr = (size_t)sAr * 256 + (size_t)gsA * 16;

    const signed char* pA0 = Ah + (size_t)m0 * 256 + thr;   // segs 0,1
    const signed char* pA1 = Al + (size_t)m0 * 256 + thr;   // seg 2
    const signed char* pB0 = Bh + (size_t)n0 * 256 + thr;   // segs 0,2
    const signed char* pB1 = Bl + (size_t)n0 * 256 + thr;   // seg 1

#define STAGE(PA, PB, KOFF, BUF) do { \
        GLDS16((PA) + (KOFF), &As[BUF][t * 16]); \
        GLDS16((PB) + (KOFF), &Bs[BUF][t * 16]); \
        GLDS16((PB) + 32768 + (KOFF), &Bs[BUF][(512 + t) * 16]); \
    } while (0)

#define BARN(N) do { \
        asm volatile("s_waitcnt vmcnt(" #N ")" ::: "memory"); \
        __builtin_amdgcn_sched_barrier(0); \
        __builtin_amdgcn_s_barrier(); \
        __builtin_amdgcn_sched_barrier(0); \
    } while (0)

    const int rboff = (lh ^ (lm & 3) ^ ((lm >> 2) & 3)) * 16;

#define TILEC(CUR, PF, FOLD) do { \
        PF; \
        i32x4 a_[4], b_[4]; \
        _Pragma("unroll") \
        for (int j = 0; j < 4; ++j) \
            b_[j] = *(const i32x4*)&Bs[CUR][(wn + j * 16 + lm) * 64 + rboff]; \
        _Pragma("unroll") \
        for (int i = 0; i < 4; ++i) \
            a_[i] = *(const i32x4*)&As[CUR][(wm + i * 16 + lm) * 64 + rboff]; \
        _Pragma("unroll") \
        for (int i = 0; i < 4; ++i) \
            _Pragma("unroll") \
            for (int j = 0; j < 4; ++j) \
                acc[i][j] = __builtin_amdgcn_mfma_i32_16x16x64_i8(a_[i], b_[j], acc[i][j], 0, 0, 0); \
        FOLD; \
    } while (0)

#define FOLDACC \
        _Pragma("unroll") \
        for (int i = 0; i < 4; ++i) \
            _Pragma("unroll") \
            for (int j = 0; j < 4; ++j) \
                acc[i][j] = acc[i][j] << 7

    // prologue: stages for tiles 0,1
    STAGE(pA0, pB0, 0, 0);
    STAGE(pA0, pB0, 64, 1);
    BARN(3);                                       // tile0's 3 loads landed
    TILEC(0, STAGE(pA0, pB0, 128, 2), (void)0);  BARN(3);   // t0, stage t2
    TILEC(1, STAGE(pA0, pB0, 192, 0), (void)0);  BARN(3);   // t1, stage t3
    TILEC(2, STAGE(pA0, pB1,   0, 1), (void)0);  BARN(3);   // t2, stage t4
    TILEC(0, STAGE(pA0, pB1,  64, 2), FOLDACC);  BARN(3);   // t3 (H done), stage t5
    TILEC(1, STAGE(pA0, pB1, 128, 0), (void)0);  BARN(3);   // t4, stage t6
    TILEC(2, STAGE(pA0, pB1, 192, 1), (void)0);  BARN(3);   // t5, stage t7
    TILEC(0, STAGE(pA1, pB0,   0, 2), (void)0);  BARN(3);   // t6, stage t8
    TILEC(1, STAGE(pA1, pB0,  64, 0), (void)0);  BARN(3);   // t7, stage t9
    TILEC(2, STAGE(pA1, pB0, 128, 1), (void)0);  BARN(3);   // t8, stage t10
    TILEC(0, STAGE(pA1, pB0, 192, 2), (void)0);  BARN(3);   // t9, stage t11
    TILEC(1, (void)0, (void)0);                  BARN(0);   // t10 (drain t11's loads)
    TILEC(2, (void)0, (void)0);                             // t11
#undef TILEC
#undef STAGE
#undef BARN
#undef FOLDACC
    __syncthreads();   // all waves done with As/Bs; redbuf reuse safe

    // u32 truncated-key epilogue: v = bias + cni - acc (>=0); key=(v>>10)<<8|code
    const float invu = 1.f / (256.f * scl[2]);
    int cni[4];
    #pragma unroll
    for (int j = 0; j < 4; ++j)
        cni[j] = (int)rintf(cnorm[n0 + wn + j * 16 + lm] * invu) + 0x20000000;

    u32* redbuf = (u32*)&As[0][0];   // 128 rows x 4 wc x 2 u32 = 4KB
    #pragma unroll
    for (int i = 0; i < 4; ++i) {
        u32 p1[4], p2[4];
        #pragma unroll
        for (int r = 0; r < 4; ++r) {
            u32 b1 = ~0u, b2 = ~0u;
            #pragma unroll
            for (int j = 0; j < 4; ++j) {
                const u32 v = (u32)(cni[j] - acc[i][j][r]);
                const u32 key = ((v >> 10) << 8) | (u32)(wn + j * 16 + lm);
                if (key < b1) { b2 = b1; b1 = key; }
                else if (key < b2) b2 = key;
            }
            p1[r] = b1; p2[r] = b2;
        }
        #pragma unroll
        for (int off = 1; off < 16; off <<= 1) {
            #pragma unroll
            for (int r = 0; r < 4; ++r) {
                const u32 o1 = __shfl_xor(p1[r], off);
                const u32 o2 = __shfl_xor(p2[r], off);
                const u32 lo = min(p1[r], o1);
                const u32 hi = max(p1[r], o1);
                p1[r] = lo;
                p2[r] = min(hi, min(p2[r], o2));
            }
        }
        if (lm == 0) {
            #pragma unroll
            for (int r = 0; r < 4; ++r) {
                const int rl = wm + i * 16 + lh * 4 + r;   // 0..127
                redbuf[rl * 8 + wc * 2 + 0] = p1[r];
                redbuf[rl * 8 + wc * 2 + 1] = p2[r];
            }
        }
    }
    __syncthreads();
    if (t < 128) {
        u32 m1 = ~0u, m2 = ~0u;
        #pragma unroll
        for (int w = 0; w < 4; ++w) {
            const u32 a1 = redbuf[t * 8 + w * 2 + 0];
            const u32 a2 = redbuf[t * 8 + w * 2 + 1];
            const u32 lo = min(m1, a1);
            const u32 hi = max(m1, a1);
            m1 = lo;
            m2 = min(hi, min(m2, a2));
        }
        wsmin[(size_t)(m0 + t) * 32 + ntile] = make_uint2(m1, m2);
    }
}

// ---------------- combine per-ntile mins; histogram; flag near-ties ----------------
__global__ void kcombine(const uint2* __restrict__ wsmin, float* __restrict__ idxf,
                         unsigned* __restrict__ rcnt, unsigned* __restrict__ rrows,
                         uint2* __restrict__ rpair, float* __restrict__ counts) {
    const int row = blockIdx.x * 256 + threadIdx.x;
    const uint2* p = wsmin + (size_t)row * 32;
    u32 m1 = ~0u, m2 = ~0u;
    int nt1 = 0, nt2 = 0;
    for (int nt = 0; nt < 32; ++nt) {
        const uint2 c = p[nt];
        if (c.x < m1) { m2 = m1; nt2 = nt1; m1 = c.x; nt1 = nt; }
        else if (c.x < m2) { m2 = c.x; nt2 = nt; }
        if (c.y < m2) { m2 = c.y; nt2 = nt; }
    }
    const int k = nt1 * 256 + (int)(m1 & 255u);
    idxf[row] = (float)k;
    atomicAdd(&counts[k], 1.0f);
    if ((m2 >> 8) - (m1 >> 8) <= RESC_KEYGAP) {
        unsigned slot = atomicAdd(rcnt, 1u);
        if (slot < RESC_CAP) {
            rrows[slot] = (unsigned)row;
            rpair[slot] = make_uint2((unsigned)k, (unsigned)(nt2 * 256 + (int)(m2 & 255u)));
        }
    }
}

// ---------------- exact fp32 pair re-score (wave per flagged row) ----------------
__global__ __launch_bounds__(256)
void krescue2(const float* __restrict__ x, const float* __restrict__ cb,
              const float* __restrict__ cnorm, const unsigned* __restrict__ rcnt,
              const unsigned* __restrict__ rrows, const uint2* __restrict__ rpair,
              float* __restrict__ idxf, float* __restrict__ counts) {
    const int lane = threadIdx.x & 63;
    const int wv = threadIdx.x >> 6;
    unsigned cnt = *rcnt; if (cnt > RESC_CAP) cnt = RESC_CAP;
    for (unsigned i = blockIdx.x * 4 + wv; i < cnt; i += gridDim.x * 4) {
        const int row = (int)rrows[i];
        const uint2 kk = rpair[i];
        const int b = row >> 12, s = row & 4095;
        float d1 = 0.f, d2 = 0.f;
        #pragma unroll
        for (int q = 0; q < 4; ++q) {
            const int c = lane + q * 64;
            const float xv = x[((size_t)(b * 256 + c)) * 4096 + s];
            d1 = fmaf(xv, cb[(size_t)kk.x * 256 + c], d1);
            d2 = fmaf(xv, cb[(size_t)kk.y * 256 + c], d2);
        }
        #pragma unroll
        for (int off = 32; off; off >>= 1) {
            d1 += __shfl_down(d1, off);
            d2 += __shfl_down(d2, off);
        }
        if (lane == 0) {
            const float dist1 = fmaf(-2.f, d1, cnorm[kk.x]);
            const float dist2 = fmaf(-2.f, d2, cnorm[kk.y]);
            const u64 p1 = ((u64)fkey(dist1) << 32) | kk.x;
            const u64 p2 = ((u64)fkey(dist2) << 32) | kk.y;
            const int knew = (int)(unsigned)((p1 < p2 ? p1 : p2) & 0xffffffffu);
            const int kold = (int)kk.x;
            if (knew != kold) {
                atomicAdd(&counts[kold], -1.0f);
                atomicAdd(&counts[knew], 1.0f);
                idxf[row] = (float)knew;
            }
        }
    }
}

// ---------------- CSR build: scan / scatter ----------------
__global__ void kscan(const float* __restrict__ counts, unsigned* __restrict__ off,
                      unsigned* __restrict__ cursor) {
    __shared__ unsigned part[256];
    const int t = threadIdx.x;
    unsigned local[32];
    unsigned s = 0;
    #pragma unroll
    for (int i = 0; i < 32; ++i) { local[i] = s; s += (unsigned)counts[t * 32 + i]; }
    part[t] = s;
    __syncthreads();
    if (t == 0) {
        unsigned run = 0;
        for (int i = 0; i < 256; ++i) { unsigned v = part[i]; part[i] = run; run += v; }
    }
    __syncthreads();
    const unsigned base = part[t];
    #pragma unroll
    for (int i = 0; i < 32; ++i) {
        unsigned o = base + local[i];
        off[t * 32 + i] = o;
        cursor[t * 32 + i] = o;
    }
}

__global__ void kscatter(const float* __restrict__ idxf, unsigned* __restrict__ cursor,
                         unsigned* __restrict__ rowlist) {
    const int n = blockIdx.x * 256 + threadIdx.x;
    const int k = (int)idxf[n];
    unsigned pos = atomicAdd(&cursor[k], 1u);
    rowlist[pos] = (unsigned)n;
}

// ---------------- quantize (gather-transpose) + e_loss ----------------
__global__ __launch_bounds__(256)
void kquant2(const float* __restrict__ x, const float* __restrict__ cb,
             const float* __restrict__ idxf, float* __restrict__ qout,
             float* __restrict__ loss_arr) {
    __shared__ int ki[64];
    __shared__ float cbt[64][257];
    const int t = threadIdx.x;
    const int bid = blockIdx.x;
    const int chunk = bid & 63;
    const int b = bid >> 6;
    const int s0 = chunk * 64;
    if (t < 64) ki[t] = (int)idxf[b * 4096 + s0 + t];
    __syncthreads();
    {
        const int lane = t & 63;
        const int rr = t >> 6;
        #pragma unroll
        for (int p = 0; p < 16; ++p) {
            const int r = p * 4 + rr;
            const float4 v = *(const float4*)(cb + (size_t)ki[r] * C_DIM + lane * 4);
            cbt[r][lane * 4 + 0] = v.x;
            cbt[r][lane * 4 + 1] = v.y;
            cbt[r][lane * 4 + 2] = v.z;
            cbt[r][lane * 4 + 3] = v.w;
        }
    }
    __syncthreads();
    const int sg = t & 15;
    const int c0 = t >> 4;
    float lsum = 0.f;
    #pragma unroll
    for (int cc = 0; cc < 16; ++cc) {
        const int c = cc * 16 + c0;
        const size_t go = ((size_t)b * C_DIM + c) * 4096 + s0 + sg * 4;
        const float4 xv = *(const float4*)(x + go);
        float qx = cbt[sg * 4 + 0][c];
        float qy = cbt[sg * 4 + 1][c];
        float qz = cbt[sg * 4 + 2][c];
        float qw = cbt[sg * 4 + 3][c];
        float4 st;
        st.x = xv.x + (qx - xv.x);
        st.y = xv.y + (qy - xv.y);
        st.z = xv.z + (qz - xv.z);
        st.w = xv.w + (qw - xv.w);
        *(float4*)(qout + go) = st;
        float dx = qx - xv.x, dy = qy - xv.y, dz = qz - xv.z, dw_ = qw - xv.w;
        lsum += dx * dx + dy * dy + dz * dz + dw_ * dw_;
    }
    #pragma unroll
    for (int off = 32; off; off >>= 1) lsum += __shfl_down(lsum, off);
    __shared__ float ps[4];
    if ((t & 63) == 0) ps[t >> 6] = lsum;
    __syncthreads();
    if (t == 0) atomicAdd(&loss_arr[bid & 255], ps[0] + ps[1] + ps[2] + ps[3]);
}

// ---------------- EMA finalize + CSR dw-sum + stats (fused) ----------------
__global__ void kfinal3(const float* __restrict__ ema_c, const float* __restrict__ ema_w,
                        const float* __restrict__ counts, const unsigned* __restrict__ off,
                        const unsigned* __restrict__ rowlist,
                        const signed char* __restrict__ Ah, const signed char* __restrict__ Al,
                        const float* __restrict__ scl,
                        float* __restrict__ nw, float* __restrict__ ncb,
                        float* __restrict__ ncnt_out,
                        const float* __restrict__ loss_arr, float* __restrict__ out) {
    const int k = blockIdx.x;
    const int t = threadIdx.x;   // 256 = one c each
    if (k < K_CODES) {
        const int cnt = (int)counts[k];
        const unsigned base = off[k];
        int a = 0;
        for (int i = 0; i < cnt; ++i) {
            const unsigned row = rowlist[base + i];
            a += (int)Ah[(size_t)row * C_DIM + t] * 128 + (int)Al[(size_t)row * C_DIM + t];
        }
        const float dwv = (float)a * (scl[0] * (1.f / 16384.f));
        const float ncnt = (DECAYF * ema_c[k] + (1.f - DECAYF) * counts[k] + EPSF)
                           / (8.f + (float)K_CODES * EPSF) * 8.f;
        const size_t o = (size_t)k * C_DIM + t;
        const float nwv = DECAYF * ema_w[o] + (1.f - DECAYF) * dwv;
        nw[o]  = nwv;
        ncb[o] = nwv / ncnt;
        if (t == 0) ncnt_out[k] = ncnt;
    } else {
        float nz = 0.f, s = 0.f;
        for (int kk = t; kk < K_CODES; kk += 256) {
            float cnt = counts[kk];
            if (cnt != 0.f) nz += 1.f;
            float p = cnt * (1.f / 32768.f);
            s += p * logf(p + 1e-10f);
        }
        float ls = loss_arr[t];
        #pragma unroll
        for (int off_ = 32; off_; off_ >>= 1) {
            s  += __shfl_down(s, off_);
            nz += __shfl_down(nz, off_);
            ls += __shfl_down(ls, off_);
        }
        __shared__ float ss[4], zz[4], ll[4];
        const int wid = t >> 6, lane = t & 63;
        if (lane == 0) { ss[wid] = s; zz[wid] = nz; ll[wid] = ls; }
        __syncthreads();
        if (t == 0) {
            float st = ss[0] + ss[1] + ss[2] + ss[3];
            float zt = zz[0] + zz[1] + zz[2] + zz[3];
            float lt = ll[0] + ll[1] + ll[2] + ll[3];
            out[OFF_ELOSS] = COMMITF * lt / 8388608.f;
            out[OFF_PERP]  = expf(-st);
            out[OFF_UNIQ]  = zt;
        }
    }
}

// ======= fallback fp32 path (used only if ws too small) =======
__global__ void knorm(const float* __restrict__ cb, float* __restrict__ cnorm) {
    const int wid  = threadIdx.x >> 6;
    const int lane = threadIdx.x & 63;
    const int row  = blockIdx.x * 4 + wid;
    const float4 v = *(const float4*)(cb + (size_t)row * C_DIM + lane * 4);
    float s = v.x * v.x + v.y * v.y + v.z * v.z + v.w * v.w;
    #pragma unroll
    for (int off = 32; off; off >>= 1) s += __shfl_down(s, off);
    if (lane == 0) cnorm[row] = s;
}

__launch_bounds__(256, 1)
__global__ void kargmin_fp32(const float* __restrict__ x, const float* __restrict__ cb,
                             const float* __restrict__ cnorm, float* __restrict__ idxf) {
    __shared__ float xs[64][256];
    __shared__ float es[64][256];
    const int t  = threadIdx.x;
    const int n0 = blockIdx.x * 64;
    const int b  = n0 >> 12;
    const int s0 = n0 & 4095;
    {
        const int r  = t & 63;
        const int c0 = t >> 6;
        const float* xb = x + (size_t)b * C_DIM * 4096 + s0 + r;
        const int sw = SWZ(r);
        #pragma unroll 8
        for (int cc = 0; cc < 64; ++cc) {
            int c = cc * 4 + c0;
            xs[r][c ^ sw] = xb[(size_t)c * 4096];
        }
    }
    const int mg  = t >> 4;
    const int ng  = t & 15;
    const int m0  = mg * 4;
    const int nn0 = ng * 4;
    const int swm = SWZ(m0);
    const int swn = SWZ(nn0);
    float minv[4] = {1e30f, 1e30f, 1e30f, 1e30f};
    int   mini[4] = {0, 0, 0, 0};
    for (int k0 = 0; k0 < K_CODES; k0 += 64) {
        __syncthreads();
        {
            const int lane = t & 63;
            const int cw   = t >> 6;
            #pragma unroll
            for (int p = 0; p < 16; ++p) {
                int code = p * 4 + cw;
                float4 v = *(const float4*)(cb + (size_t)(k0 + code) * C_DIM + lane * 4);
                *(float4*)&es[code][(lane * 4) ^ SWZ(code)] = v;
            }
        }
        float cn[4];
        #pragma unroll
        for (int j = 0; j < 4; ++j) cn[j] = cnorm[k0 + nn0 + j];
        __syncthreads();
        float acc[4][4];
        #pragma unroll
        for (int i = 0; i < 4; ++i)
            #pragma unroll
            for (int j = 0; j < 4; ++j) acc[i][j] = 0.f;
        #pragma unroll 4
        for (int c = 0; c < C_DIM; c += 4) {
            float4 xa[4], eb[4];
            #pragma unroll
            for (int i = 0; i < 4; ++i) xa[i] = *(const float4*)&xs[m0 + i][c ^ swm];
            #pragma unroll
            for (int j = 0; j < 4; ++j) eb[j] = *(const float4*)&es[nn0 + j][c ^ swn];
            #pragma unroll
            for (int i = 0; i < 4; ++i)
                #pragma unroll
                for (int j = 0; j < 4; ++j)
                    acc[i][j] += xa[i].x * eb[j].x + xa[i].y * eb[j].y +
                                 xa[i].z * eb[j].z + xa[i].w * eb[j].w;
        }
        #pragma unroll
        for (int j = 0; j < 4; ++j) {
            const int kg = k0 + nn0 + j;
            #pragma unroll
            for (int i = 0; i < 4; ++i) {
                float dist = fmaf(-2.f, acc[i][j], cn[j]);
                if (dist < minv[i]) { minv[i] = dist; mini[i] = kg; }
            }
        }
    }
    #pragma unroll
    for (int off = 1; off < 16; off <<= 1) {
        #pragma unroll
        for (int i = 0; i < 4; ++i) {
            float ov = __shfl_xor(minv[i], off);
            int   oi = __shfl_xor(mini[i], off);
            if (ov < minv[i] || (ov == minv[i] && oi < mini[i])) { minv[i] = ov; mini[i] = oi; }
        }
    }
    if (ng == 0) {
        #pragma unroll
        for (int i = 0; i < 4; ++i) idxf[n0 + m0 + i] = (float)mini[i];
    }
}

__global__ void kquant_legacy(const float* __restrict__ x, const float* __restrict__ cb,
                              const float* __restrict__ idxf, float* __restrict__ qout,
                              float* __restrict__ dw, float* __restrict__ counts,
                              float* __restrict__ loss_arr) {
    const int t   = threadIdx.x;
    const int bid = blockIdx.x;
    const int sc  = bid & 15;
    const int c   = (bid >> 4) & 255;
    const int b   = bid >> 12;
    const int s   = sc * 256 + t;
    const int n   = b * 4096 + s;
    const int k   = (int)idxf[n];
    const size_t xoff = ((size_t)b * C_DIM + c) * 4096 + s;
    const float xv = x[xoff];
    const float q  = cb[(size_t)k * C_DIM + c];
    qout[xoff] = xv + (q - xv);
    atomicAdd(&dw[(size_t)k * C_DIM + c], xv);
    if (c == 0) atomicAdd(&counts[k], 1.0f);
    float d = q - xv;
    float p = d * d;
    #pragma unroll
    for (int off = 32; off; off >>= 1) p += __shfl_down(p, off);
    __shared__ float ps[4];
    if ((t & 63) == 0) ps[t >> 6] = p;
    __syncthreads();
    if (t == 0) atomicAdd(&loss_arr[bid & 255], ps[0] + ps[1] + ps[2] + ps[3]);
}

__global__ void kstats_legacy(const float* __restrict__ counts, const float* __restrict__ loss_arr,
                              float* __restrict__ out) {
    const int t = threadIdx.x;
    float nz = 0.f, s = 0.f;
    for (int k = t; k < K_CODES; k += 256) {
        float cnt = counts[k];
        if (cnt != 0.f) nz += 1.f;
        float p = cnt * (1.f / 32768.f);
        s += p * logf(p + 1e-10f);
    }
    float ls = loss_arr[t];
    #pragma unroll
    for (int off = 32; off; off >>= 1) {
        s  += __shfl_down(s, off);
        nz += __shfl_down(nz, off);
        ls += __shfl_down(ls, off);
    }
    __shared__ float ss[4], zz[4], ll[4];
    const int wid = t >> 6, lane = t & 63;
    if (lane == 0) { ss[wid] = s; zz[wid] = nz; ll[wid] = ls; }
    __syncthreads();
    if (t == 0) {
        out[OFF_ELOSS] = COMMITF * (ll[0] + ll[1] + ll[2] + ll[3]) / 8388608.f;
        out[OFF_PERP]  = expf(-(ss[0] + ss[1] + ss[2] + ss[3]));
        out[OFF_UNIQ]  = zz[0] + zz[1] + zz[2] + zz[3];
    }
}

__global__ void kfinal_legacy(const float* __restrict__ ema_c, const float* __restrict__ ema_w,
                              float* __restrict__ counts, float* __restrict__ dw,
                              float* __restrict__ ncb) {
    const int k = blockIdx.x;
    const int c = threadIdx.x;
    const float cnt  = counts[k];
    const float ncnt = (DECAYF * ema_c[k] + (1.f - DECAYF) * cnt + EPSF)
                       / (8.f + (float)K_CODES * EPSF) * 8.f;
    const size_t o = (size_t)k * C_DIM + c;
    const float nw = DECAYF * ema_w[o] + (1.f - DECAYF) * dw[o];
    __syncthreads();
    dw[o]  = nw;
    ncb[o] = nw / ncnt;
    if (c == 0) counts[k] = ncnt;
}

extern "C" void kernel_launch(void* const* d_in, const int* in_sizes, int n_in,
                              void* d_out, int out_size, void* d_ws, size_t ws_size,
                              hipStream_t stream) {
    const float* x     = (const float*)d_in[0];
    const float* cb    = (const float*)d_in[1];
    const float* ema_c = (const float*)d_in[2];
    const float* ema_w = (const float*)d_in[3];
    float* out = (float*)d_out;

    float* qout = out + OFF_QUANT;
    float* ncb  = out + OFF_NCB;
    float* ncnt = out + OFF_NCNT;
    float* nw   = out + OFF_NW;
    float* idxf = out + OFF_IDX;

    const size_t szA = (size_t)N_ROWS * C_DIM;    // 8388608 bytes per plane
    const size_t szB = (size_t)K_CODES * C_DIM;   // 2097152
    const size_t fcount = 8192 + 256 + 8192 + 4 + 2560;
    const size_t need = 2 * szA + 2 * szB + fcount * 4
                      + RESC_CAP * 8 + RESC_CAP * 4 + 4 + 8192 * 4 * 2 + 32768 * 4 + 64;
    const bool use_i8 = ws_size >= need;

    if (use_i8) {
        signed char* Ah = (signed char*)d_ws;
        signed char* Al = Ah + szA;
        signed char* Bh = Al + szA;
        signed char* Bl = Bh + szB;
        float* fbase      = (float*)(Bl + szB);
        float* cnorm      = fbase;
        float* loss_arr   = fbase + 8192;
        float* counts_raw = fbase + 8448;
        float* scl        = fbase + 16640;
        float* maxbuf     = fbase + 16644;
        uint2* rpair      = (uint2*)(fbase + fcount);
        unsigned* rrows   = (unsigned*)(rpair + RESC_CAP);
        unsigned* rcnt    = rrows + RESC_CAP;
        unsigned* off     = rcnt + 1;
        unsigned* cursor  = off + K_CODES;
        unsigned* rowlist = cursor + K_CODES;
        uint2* wsmin = (uint2*)(out + OFF_QUANT);   // 8.4 MB, consumed before kquant2 writes qout

        kmax<<<2560, 256, 0, stream>>>(x, cb, maxbuf);
        kscale<<<1, 256, 0, stream>>>(maxbuf, scl, counts_raw, loss_arr, rcnt);
        kprep<<<4096, 256, 0, stream>>>(cb, x, Ah, Al, Bh, Bl, cnorm, scl);
        kargmin_i8<<<8192, 512, 0, stream>>>(Ah, Al, Bh, Bl, cnorm, scl, wsmin);
        kcombine<<<N_ROWS / 256, 256, 0, stream>>>(wsmin, idxf, rcnt, rrows, rpair, counts_raw);
        krescue2<<<256, 256, 0, stream>>>(x, cb, cnorm, rcnt, rrows, rpair, idxf, counts_raw);
        kscan<<<1, 256, 0, stream>>>(counts_raw, off, cursor);
        kscatter<<<N_ROWS / 256, 256, 0, stream>>>(idxf, cursor, rowlist);
        kquant2<<<512, 256, 0, stream>>>(x, cb, idxf, qout, loss_arr);
        kfinal3<<<K_CODES + 1, C_DIM, 0, stream>>>(ema_c, ema_w, counts_raw, off, rowlist,
                                                   Ah, Al, scl, nw, ncb, ncnt, loss_arr, out);
    } else {
        float* cnorm = (float*)d_ws;
        float* loss_arr = cnorm + K_CODES;
        hipMemsetAsync(ncnt, 0, K_CODES * sizeof(float), stream);
        hipMemsetAsync(nw, 0, (size_t)K_CODES * C_DIM * sizeof(float), stream);
        hipMemsetAsync(loss_arr, 0, 256 * sizeof(float), stream);
        knorm<<<K_CODES / 4, 256, 0, stream>>>(cb, cnorm);
        kargmin_fp32<<<N_ROWS / 64, 256, 0, stream>>>(x, cb, cnorm, idxf);
        kquant_legacy<<<32768, 256, 0, stream>>>(x, cb, idxf, qout, nw, ncnt, loss_arr);
        kstats_legacy<<<1, 256, 0, stream>>>(ncnt, loss_arr, out);
        kfinal_legacy<<<K_CODES, C_DIM, 0, stream>>>(ema_c, ema_w, ncnt, nw, ncb);
    }
}

// Round 18
// 452.252 us; speedup vs baseline: 1.3923x; 1.0255x over previous
//
#include <hip/hip_runtime.h>
#include <hip/hip_bf16.h>
#include <stdint.h>

#define N_ROWS 32768
#define K_CODES 8192
#define C_DIM 256
#define DECAYF 0.95f
#define COMMITF 0.25f
#define EPSF 1e-5f
#define RESC_KEYGAP 2u
#define RESC_CAP 16384

// d_out layout (floats), reference return order
#define OFF_QUANT 0
#define OFF_ELOSS 8388608
#define OFF_PERP  8388609
#define OFF_UNIQ  8388610
#define OFF_NCB   8388611
#define OFF_NCNT  10485763
#define OFF_NW    10493955
#define OFF_IDX   12591107

typedef float f32x4 __attribute__((ext_vector_type(4)));
typedef int i32x4 __attribute__((ext_vector_type(4)));
typedef unsigned long long u64;
typedef unsigned int u32;

#define SWZ(r) ((((r) >> 2) & 7) << 2)

#if defined(__has_builtin)
#if __has_builtin(__builtin_amdgcn_global_load_lds)
#define HAVE_GLDS 1
#endif
#endif
#ifdef HAVE_GLDS
#define GLDS16(g, l) __builtin_amdgcn_global_load_lds( \
    (const __attribute__((address_space(1))) void*)(uintptr_t)(g), \
    (__attribute__((address_space(3))) void*)(uint32_t)(uintptr_t)(l), 16, 0, 0)
#else
#define GLDS16(g, l) do { *(float4*)(l) = *(const float4*)(g); } while (0)
#endif

__device__ __forceinline__ uint32_t fkey(float f) {
    uint32_t b = __float_as_uint(f);
    return b ^ ((uint32_t)((int32_t)b >> 31) | 0x80000000u);
}
// 14-bit fixed-point -> two signed i8 (h*128 + l), l in [-64,63]
__device__ __forceinline__ void enc8(float v, float inv, signed char& h, signed char& l) {
    int q = __float2int_rn(v * inv);
    q = q > 16319 ? 16319 : (q < -16320 ? -16320 : q);
    int hh = (q + 64) >> 7;
    h = (signed char)hh;
    l = (signed char)(q - (hh << 7));
}

// ---------------- per-block absmax of x (blocks 0-2047) and cb (2048-2559) ----------------
__global__ __launch_bounds__(256)
void kmax(const float* __restrict__ x, const float* __restrict__ cb, float* __restrict__ maxbuf) {
    const int bid = blockIdx.x, t = threadIdx.x;
    const float* src = bid < 2048 ? x : cb;
    const size_t base = bid < 2048 ? (size_t)bid * 4096 : (size_t)(bid - 2048) * 4096;
    float m = 0.f;
    #pragma unroll
    for (int i = 0; i < 4; ++i) {
        const float4 v = *(const float4*)(src + base + ((size_t)i * 256 + t) * 4);
        m = fmaxf(m, fmaxf(fmaxf(fabsf(v.x), fabsf(v.y)), fmaxf(fabsf(v.z), fabsf(v.w))));
    }
    #pragma unroll
    for (int off = 32; off; off >>= 1) m = fmaxf(m, __shfl_down(m, off));
    __shared__ float ps[4];
    if ((t & 63) == 0) ps[t >> 6] = m;
    __syncthreads();
    if (t == 0) maxbuf[bid] = fmaxf(fmaxf(ps[0], ps[1]), fmaxf(ps[2], ps[3]));
}

// ---------------- final scales + zero accumulators ----------------
__global__ void kscale(const float* __restrict__ maxbuf, float* __restrict__ scl,
                       float* __restrict__ counts, float* __restrict__ loss_arr,
                       unsigned* __restrict__ rcnt) {
    const int t = threadIdx.x;
    float mx = 0.f, me = 0.f;
    for (int i = t; i < 2048; i += 256) mx = fmaxf(mx, maxbuf[i]);
    for (int i = 2048 + t; i < 2560; i += 256) me = fmaxf(me, maxbuf[i]);
    #pragma unroll
    for (int off = 32; off; off >>= 1) {
        mx = fmaxf(mx, __shfl_down(mx, off));
        me = fmaxf(me, __shfl_down(me, off));
    }
    __shared__ float px[4], pe[4];
    if ((t & 63) == 0) { px[t >> 6] = mx; pe[t >> 6] = me; }
    __syncthreads();
    if (t == 0) {
        const float Sx = fmaxf(fmaxf(px[0], px[1]), fmaxf(px[2], px[3])) * (16384.f / 16320.f) + 1e-20f;
        const float Se = fmaxf(fmaxf(pe[0], pe[1]), fmaxf(pe[2], pe[3])) * (16384.f / 16320.f) + 1e-20f;
        scl[0] = Sx; scl[1] = Se; scl[2] = Sx * Se / 268435456.f;
        *rcnt = 0u;
    }
    for (int i = t; i < K_CODES; i += 256) counts[i] = 0.f;
    loss_arr[t] = 0.f;
}

// ---------------- encode cb (blocks 0-2047, + cnorm) and x (2048-4095, transpose) ----------------
__global__ __launch_bounds__(256)
void kprep(const float* __restrict__ cb, const float* __restrict__ x,
           signed char* __restrict__ Ah, signed char* __restrict__ Al,
           signed char* __restrict__ Bh, signed char* __restrict__ Bl,
           float* __restrict__ cnorm, const float* __restrict__ scl) {
    const int bid = blockIdx.x;
    const int t = threadIdx.x;
    if (bid < 2048) {
        const float inve = 16384.f / scl[1];
        const size_t i4 = ((size_t)bid * 256 + t) * 4;
        const float4 v = *(const float4*)(cb + i4);
        signed char h0, h1, h2, h3, l0, l1, l2, l3;
        enc8(v.x, inve, h0, l0); enc8(v.y, inve, h1, l1);
        enc8(v.z, inve, h2, l2); enc8(v.w, inve, h3, l3);
        *(char4*)(Bh + i4) = make_char4(h0, h1, h2, h3);
        *(char4*)(Bl + i4) = make_char4(l0, l1, l2, l3);
        float s = v.x * v.x + v.y * v.y + v.z * v.z + v.w * v.w;
        #pragma unroll
        for (int off = 32; off; off >>= 1) s += __shfl_down(s, off);
        if ((t & 63) == 0) cnorm[i4 >> 8] = s;
    } else {
        const float invx = 16384.f / scl[0];
        __shared__ float xt[64][65];
        const int xb_id = bid - 2048;       // 8 b * 4 ct * 64 st = 2048
        const int st = xb_id & 63;
        const int ct = (xb_id >> 6) & 3;
        const int b  = xb_id >> 8;
        const float* xb = x + ((size_t)b * C_DIM + ct * 64) * 4096 + st * 64;
        {
            const int s_l = t & 63, c0 = t >> 6;
            #pragma unroll
            for (int cc = 0; cc < 16; ++cc) {
                int c_l = cc * 4 + c0;
                xt[c_l][s_l] = xb[(size_t)c_l * 4096 + s_l];
            }
        }
        __syncthreads();
        const int c2 = (t & 31) * 2;
        const int s0 = t >> 5;
        #pragma unroll
        for (int ww = 0; ww < 8; ++ww) {
            int s_o = ww * 8 + s0;
            signed char h0, l0, h1, l1;
            enc8(xt[c2][s_o], invx, h0, l0);
            enc8(xt[c2 + 1][s_o], invx, h1, l1);
            size_t off = ((size_t)(b * 4096 + st * 64 + s_o)) * C_DIM + ct * 64 + c2;
            *(char2*)(Ah + off) = make_char2(h0, h1);
            *(char2*)(Al + off) = make_char2(l0, l1);
        }
    }
}

// ---------------- i8 MFMA distance GEMM + per-row top-2 argmin ----------------
// 128x256 tile, 8 waves (2Mx4N), per-wave 64x64 (acc[4][4]).
// BK=64 i8; 12 K-tiles: 0-3 (h,h), <<7, 4-7 (h,l), 8-11 (l,h).
// DEPTH-2 pipeline: 3 LDS buffers; tile-end = counted s_waitcnt vmcnt(3)
// + s_barrier (T4). s_setprio(1) around MFMA cluster (T5 -- pays only with
// the role-split schedule that counted-vmcnt creates).
__global__ __launch_bounds__(512, 4)
void kargmin_i8(const signed char* __restrict__ Ah, const signed char* __restrict__ Al,
                const signed char* __restrict__ Bh, const signed char* __restrict__ Bl,
                const float* __restrict__ cnorm, const float* __restrict__ scl,
                uint2* __restrict__ wsmin) {
    __shared__ unsigned char As[3][128 * 64];   // 8KB x3
    __shared__ unsigned char Bs[3][256 * 64];   // 16KB x3

    const int t = threadIdx.x;
    const int lane = t & 63;
    const int wid = t >> 6;
    const int xcd = blockIdx.x & 7;
    const int ii = blockIdx.x >> 3;              // 0..1023 within XCD
    const int ntile = xcd * 4 + (ii & 3);        // 0..31
    const int mtile = ii >> 2;                   // 0..255
    const int m0 = mtile * 128;
    const int n0 = ntile * 256;
    const int wr = wid >> 2;                     // 0..1
    const int wc = wid & 3;                      // 0..3
    const int wm = wr * 64;
    const int wn = wc * 64;
    const int lm = lane & 15;
    const int lh = lane >> 4;

    i32x4 acc[4][4];
    #pragma unroll
    for (int i = 0; i < 4; ++i)
        #pragma unroll
        for (int j = 0; j < 4; ++j) acc[i][j] = (i32x4){0, 0, 0, 0};

    // staging: rows of 64B = 4 slots of 16B; swizzle slot ^= (row&3)^((row>>2)&3)
    const int sAr = t >> 2;          // A row 0..127 (B rows sAr and 128+sAr, same swizzle)
    const int ssl = t & 3;
    const int gsA = ssl ^ (sAr & 3) ^ ((sAr >> 2) & 3);
    const size_t thr = (size_t)sAr * 256 + (size_t)gsA * 16;

    const signed char* pA0 = Ah + (size_t)m0 * 256 + thr;   // segs 0,1
    const signed char* pA1 = Al + (size_t)m0 * 256 + thr;   // seg 2
    const signed char* pB0 = Bh + (size_t)n0 * 256 + thr;   // segs 0,2
    const signed char* pB1 = Bl + (size_t)n0 * 256 + thr;   // seg 1

#define STAGE(PA, PB, KOFF, BUF) do { \
        GLDS16((PA) + (KOFF), &As[BUF][t * 16]); \
        GLDS16((PB) + (KOFF), &Bs[BUF][t * 16]); \
        GLDS16((PB) + 32768 + (KOFF), &Bs[BUF][(512 + t) * 16]); \
    } while (0)

#define BARN(N) do { \
        asm volatile("s_waitcnt vmcnt(" #N ")" ::: "memory"); \
        __builtin_amdgcn_sched_barrier(0); \
        __builtin_amdgcn_s_barrier(); \
        __builtin_amdgcn_sched_barrier(0); \
    } while (0)

    const int rboff = (lh ^ (lm & 3) ^ ((lm >> 2) & 3)) * 16;

#define TILEC(CUR, PF, FOLD) do { \
        PF; \
        i32x4 a_[4], b_[4]; \
        _Pragma("unroll") \
        for (int j = 0; j < 4; ++j) \
            b_[j] = *(const i32x4*)&Bs[CUR][(wn + j * 16 + lm) * 64 + rboff]; \
        _Pragma("unroll") \
        for (int i = 0; i < 4; ++i) \
            a_[i] = *(const i32x4*)&As[CUR][(wm + i * 16 + lm) * 64 + rboff]; \
        __builtin_amdgcn_s_setprio(1); \
        _Pragma("unroll") \
        for (int i = 0; i < 4; ++i) \
            _Pragma("unroll") \
            for (int j = 0; j < 4; ++j) \
                acc[i][j] = __builtin_amdgcn_mfma_i32_16x16x64_i8(a_[i], b_[j], acc[i][j], 0, 0, 0); \
        __builtin_amdgcn_s_setprio(0); \
        FOLD; \
    } while (0)

#define FOLDACC \
        _Pragma("unroll") \
        for (int i = 0; i < 4; ++i) \
            _Pragma("unroll") \
            for (int j = 0; j < 4; ++j) \
                acc[i][j] = acc[i][j] << 7

    // prologue: stages for tiles 0,1
    STAGE(pA0, pB0, 0, 0);
    STAGE(pA0, pB0, 64, 1);
    BARN(3);                                       // tile0's 3 loads landed
    TILEC(0, STAGE(pA0, pB0, 128, 2), (void)0);  BARN(3);   // t0, stage t2
    TILEC(1, STAGE(pA0, pB0, 192, 0), (void)0);  BARN(3);   // t1, stage t3
    TILEC(2, STAGE(pA0, pB1,   0, 1), (void)0);  BARN(3);   // t2, stage t4
    TILEC(0, STAGE(pA0, pB1,  64, 2), FOLDACC);  BARN(3);   // t3 (H done), stage t5
    TILEC(1, STAGE(pA0, pB1, 128, 0), (void)0);  BARN(3);   // t4, stage t6
    TILEC(2, STAGE(pA0, pB1, 192, 1), (void)0);  BARN(3);   // t5, stage t7
    TILEC(0, STAGE(pA1, pB0,   0, 2), (void)0);  BARN(3);   // t6, stage t8
    TILEC(1, STAGE(pA1, pB0,  64, 0), (void)0);  BARN(3);   // t7, stage t9
    TILEC(2, STAGE(pA1, pB0, 128, 1), (void)0);  BARN(3);   // t8, stage t10
    TILEC(0, STAGE(pA1, pB0, 192, 2), (void)0);  BARN(3);   // t9, stage t11
    TILEC(1, (void)0, (void)0);                  BARN(0);   // t10 (drain t11's loads)
    TILEC(2, (void)0, (void)0);                             // t11
#undef TILEC
#undef STAGE
#undef BARN
#undef FOLDACC
    __syncthreads();   // all waves done with As/Bs; redbuf reuse safe

    // u32 truncated-key epilogue: v = bias + cni - acc (>=0); key=(v>>10)<<8|code
    const float invu = 1.f / (256.f * scl[2]);
    int cni[4];
    #pragma unroll
    for (int j = 0; j < 4; ++j)
        cni[j] = (int)rintf(cnorm[n0 + wn + j * 16 + lm] * invu) + 0x20000000;

    u32* redbuf = (u32*)&As[0][0];   // 128 rows x 4 wc x 2 u32 = 4KB
    #pragma unroll
    for (int i = 0; i < 4; ++i) {
        u32 p1[4], p2[4];
        #pragma unroll
        for (int r = 0; r < 4; ++r) {
            u32 b1 = ~0u, b2 = ~0u;
            #pragma unroll
            for (int j = 0; j < 4; ++j) {
                const u32 v = (u32)(cni[j] - acc[i][j][r]);
                const u32 key = ((v >> 10) << 8) | (u32)(wn + j * 16 + lm);
                if (key < b1) { b2 = b1; b1 = key; }
                else if (key < b2) b2 = key;
            }
            p1[r] = b1; p2[r] = b2;
        }
        #pragma unroll
        for (int off = 1; off < 16; off <<= 1) {
            #pragma unroll
            for (int r = 0; r < 4; ++r) {
                const u32 o1 = __shfl_xor(p1[r], off);
                const u32 o2 = __shfl_xor(p2[r], off);
                const u32 lo = min(p1[r], o1);
                const u32 hi = max(p1[r], o1);
                p1[r] = lo;
                p2[r] = min(hi, min(p2[r], o2));
            }
        }
        if (lm == 0) {
            #pragma unroll
            for (int r = 0; r < 4; ++r) {
                const int rl = wm + i * 16 + lh * 4 + r;   // 0..127
                redbuf[rl * 8 + wc * 2 + 0] = p1[r];
                redbuf[rl * 8 + wc * 2 + 1] = p2[r];
            }
        }
    }
    __syncthreads();
    if (t < 128) {
        u32 m1 = ~0u, m2 = ~0u;
        #pragma unroll
        for (int w = 0; w < 4; ++w) {
            const u32 a1 = redbuf[t * 8 + w * 2 + 0];
            const u32 a2 = redbuf[t * 8 + w * 2 + 1];
            const u32 lo = min(m1, a1);
            const u32 hi = max(m1, a1);
            m1 = lo;
            m2 = min(hi, min(m2, a2));
        }
        wsmin[(size_t)(m0 + t) * 32 + ntile] = make_uint2(m1, m2);
    }
}

// ---------------- combine + histogram + INLINE fp32 pair rescue (fused) ----------------
__global__ __launch_bounds__(256)
void kcombine(const uint2* __restrict__ wsmin, float* __restrict__ idxf,
              const float* __restrict__ x, const float* __restrict__ cb,
              const float* __restrict__ cnorm, float* __restrict__ counts) {
    __shared__ unsigned frow[256];
    __shared__ uint2 fpair[256];
    __shared__ unsigned fn;
    const int t = threadIdx.x;
    if (t == 0) fn = 0u;
    __syncthreads();

    const int row = blockIdx.x * 256 + t;
    const uint2* p = wsmin + (size_t)row * 32;
    u32 m1 = ~0u, m2 = ~0u;
    int nt1 = 0, nt2 = 0;
    for (int nt = 0; nt < 32; ++nt) {
        const uint2 c = p[nt];
        if (c.x < m1) { m2 = m1; nt2 = nt1; m1 = c.x; nt1 = nt; }
        else if (c.x < m2) { m2 = c.x; nt2 = nt; }
        if (c.y < m2) { m2 = c.y; nt2 = nt; }
    }
    const int k = nt1 * 256 + (int)(m1 & 255u);
    idxf[row] = (float)k;
    atomicAdd(&counts[k], 1.0f);
    if ((m2 >> 8) - (m1 >> 8) <= RESC_KEYGAP) {
        const unsigned slot = atomicAdd(&fn, 1u);   // <= 256 by construction
        frow[slot] = (unsigned)row;
        fpair[slot] = make_uint2((unsigned)k, (unsigned)(nt2 * 256 + (int)(m2 & 255u)));
    }
    __syncthreads();

    // phase 2: waves cooperatively pair-rescore flagged rows (exact fp32)
    const unsigned nf = fn;
    const int lane = t & 63;
    const int wv = t >> 6;
    for (unsigned i = wv; i < nf; i += 4) {
        const int row2 = (int)frow[i];
        const uint2 kk = fpair[i];
        const int b = row2 >> 12, s = row2 & 4095;
        float d1 = 0.f, d2 = 0.f;
        #pragma unroll
        for (int q = 0; q < 4; ++q) {
            const int c = lane + q * 64;
            const float xv = x[((size_t)(b * 256 + c)) * 4096 + s];
            d1 = fmaf(xv, cb[(size_t)kk.x * 256 + c], d1);
            d2 = fmaf(xv, cb[(size_t)kk.y * 256 + c], d2);
        }
        #pragma unroll
        for (int off = 32; off; off >>= 1) {
            d1 += __shfl_down(d1, off);
            d2 += __shfl_down(d2, off);
        }
        if (lane == 0) {
            const float dist1 = fmaf(-2.f, d1, cnorm[kk.x]);
            const float dist2 = fmaf(-2.f, d2, cnorm[kk.y]);
            const u64 p1 = ((u64)fkey(dist1) << 32) | kk.x;
            const u64 p2 = ((u64)fkey(dist2) << 32) | kk.y;
            const int knew = (int)(unsigned)((p1 < p2 ? p1 : p2) & 0xffffffffu);
            const int kold = (int)kk.x;
            if (knew != kold) {
                atomicAdd(&counts[kold], -1.0f);
                atomicAdd(&counts[knew], 1.0f);
                idxf[row2] = (float)knew;
            }
        }
    }
}

// ---------------- CSR build: scan / scatter ----------------
__global__ void kscan(const float* __restrict__ counts, unsigned* __restrict__ off,
                      unsigned* __restrict__ cursor) {
    __shared__ unsigned part[256];
    const int t = threadIdx.x;
    unsigned local[32];
    unsigned s = 0;
    #pragma unroll
    for (int i = 0; i < 32; ++i) { local[i] = s; s += (unsigned)counts[t * 32 + i]; }
    part[t] = s;
    __syncthreads();
    if (t == 0) {
        unsigned run = 0;
        for (int i = 0; i < 256; ++i) { unsigned v = part[i]; part[i] = run; run += v; }
    }
    __syncthreads();
    const unsigned base = part[t];
    #pragma unroll
    for (int i = 0; i < 32; ++i) {
        unsigned o = base + local[i];
        off[t * 32 + i] = o;
        cursor[t * 32 + i] = o;
    }
}

__global__ void kscatter(const float* __restrict__ idxf, unsigned* __restrict__ cursor,
                         unsigned* __restrict__ rowlist) {
    const int n = blockIdx.x * 256 + threadIdx.x;
    const int k = (int)idxf[n];
    unsigned pos = atomicAdd(&cursor[k], 1u);
    rowlist[pos] = (unsigned)n;
}

// ---------------- quantize (gather-transpose) + e_loss ----------------
__global__ __launch_bounds__(256)
void kquant2(const float* __restrict__ x, const float* __restrict__ cb,
             const float* __restrict__ idxf, float* __restrict__ qout,
             float* __restrict__ loss_arr) {
    __shared__ int ki[64];
    __shared__ float cbt[64][257];
    const int t = threadIdx.x;
    const int bid = blockIdx.x;
    const int chunk = bid & 63;
    const int b = bid >> 6;
    const int s0 = chunk * 64;
    if (t < 64) ki[t] = (int)idxf[b * 4096 + s0 + t];
    __syncthreads();
    {
        const int lane = t & 63;
        const int rr = t >> 6;
        #pragma unroll
        for (int p = 0; p < 16; ++p) {
            const int r = p * 4 + rr;
            const float4 v = *(const float4*)(cb + (size_t)ki[r] * C_DIM + lane * 4);
            cbt[r][lane * 4 + 0] = v.x;
            cbt[r][lane * 4 + 1] = v.y;
            cbt[r][lane * 4 + 2] = v.z;
            cbt[r][lane * 4 + 3] = v.w;
        }
    }
    __syncthreads();
    const int sg = t & 15;
    const int c0 = t >> 4;
    float lsum = 0.f;
    #pragma unroll
    for (int cc = 0; cc < 16; ++cc) {
        const int c = cc * 16 + c0;
        const size_t go = ((size_t)b * C_DIM + c) * 4096 + s0 + sg * 4;
        const float4 xv = *(const float4*)(x + go);
        float qx = cbt[sg * 4 + 0][c];
        float qy = cbt[sg * 4 + 1][c];
        float qz = cbt[sg * 4 + 2][c];
        float qw = cbt[sg * 4 + 3][c];
        float4 st;
        st.x = xv.x + (qx - xv.x);
        st.y = xv.y + (qy - xv.y);
        st.z = xv.z + (qz - xv.z);
        st.w = xv.w + (qw - xv.w);
        *(float4*)(qout + go) = st;
        float dx = qx - xv.x, dy = qy - xv.y, dz = qz - xv.z, dw_ = qw - xv.w;
        lsum += dx * dx + dy * dy + dz * dz + dw_ * dw_;
    }
    #pragma unroll
    for (int off = 32; off; off >>= 1) lsum += __shfl_down(lsum, off);
    __shared__ float ps[4];
    if ((t & 63) == 0) ps[t >> 6] = lsum;
    __syncthreads();
    if (t == 0) atomicAdd(&loss_arr[bid & 255], ps[0] + ps[1] + ps[2] + ps[3]);
}

// ---------------- EMA finalize + CSR dw-sum + stats (fused) ----------------
__global__ void kfinal3(const float* __restrict__ ema_c, const float* __restrict__ ema_w,
                        const float* __restrict__ counts, const unsigned* __restrict__ off,
                        const unsigned* __restrict__ rowlist,
                        const signed char* __restrict__ Ah, const signed char* __restrict__ Al,
                        const float* __restrict__ scl,
                        float* __restrict__ nw, float* __restrict__ ncb,
                        float* __restrict__ ncnt_out,
                        const float* __restrict__ loss_arr, float* __restrict__ out) {
    const int k = blockIdx.x;
    const int t = threadIdx.x;   // 256 = one c each
    if (k < K_CODES) {
        const int cnt = (int)counts[k];
        const unsigned base = off[k];
        int a = 0;
        for (int i = 0; i < cnt; ++i) {
            const unsigned row = rowlist[base + i];
            a += (int)Ah[(size_t)row * C_DIM + t] * 128 + (int)Al[(size_t)row * C_DIM + t];
        }
        const float dwv = (float)a * (scl[0] * (1.f / 16384.f));
        const float ncnt = (DECAYF * ema_c[k] + (1.f - DECAYF) * counts[k] + EPSF)
                           / (8.f + (float)K_CODES * EPSF) * 8.f;
        const size_t o = (size_t)k * C_DIM + t;
        const float nwv = DECAYF * ema_w[o] + (1.f - DECAYF) * dwv;
        nw[o]  = nwv;
        ncb[o] = nwv / ncnt;
        if (t == 0) ncnt_out[k] = ncnt;
    } else {
        float nz = 0.f, s = 0.f;
        for (int kk = t; kk < K_CODES; kk += 256) {
            float cnt = counts[kk];
            if (cnt != 0.f) nz += 1.f;
            float p = cnt * (1.f / 32768.f);
            s += p * logf(p + 1e-10f);
        }
        float ls = loss_arr[t];
        #pragma unroll
        for (int off_ = 32; off_; off_ >>= 1) {
            s  += __shfl_down(s, off_);
            nz += __shfl_down(nz, off_);
            ls += __shfl_down(ls, off_);
        }
        __shared__ float ss[4], zz[4], ll[4];
        const int wid = t >> 6, lane = t & 63;
        if (lane == 0) { ss[wid] = s; zz[wid] = nz; ll[wid] = ls; }
        __syncthreads();
        if (t == 0) {
            float st = ss[0] + ss[1] + ss[2] + ss[3];
            float zt = zz[0] + zz[1] + zz[2] + zz[3];
            float lt = ll[0] + ll[1] + ll[2] + ll[3];
            out[OFF_ELOSS] = COMMITF * lt / 8388608.f;
            out[OFF_PERP]  = expf(-st);
            out[OFF_UNIQ]  = zt;
        }
    }
}

// ======= fallback fp32 path (used only if ws too small) =======
__global__ void knorm(const float* __restrict__ cb, float* __restrict__ cnorm) {
    const int wid  = threadIdx.x >> 6;
    const int lane = threadIdx.x & 63;
    const int row  = blockIdx.x * 4 + wid;
    const float4 v = *(const float4*)(cb + (size_t)row * C_DIM + lane * 4);
    float s = v.x * v.x + v.y * v.y + v.z * v.z + v.w * v.w;
    #pragma unroll
    for (int off = 32; off; off >>= 1) s += __shfl_down(s, off);
    if (lane == 0) cnorm[row] = s;
}

__launch_bounds__(256, 1)
__global__ void kargmin_fp32(const float* __restrict__ x, const float* __restrict__ cb,
                             const float* __restrict__ cnorm, float* __restrict__ idxf) {
    __shared__ float xs[64][256];
    __shared__ float es[64][256];
    const int t  = threadIdx.x;
    const int n0 = blockIdx.x * 64;
    const int b  = n0 >> 12;
    const int s0 = n0 & 4095;
    {
        const int r  = t & 63;
        const int c0 = t >> 6;
        const float* xb = x + (size_t)b * C_DIM * 4096 + s0 + r;
        const int sw = SWZ(r);
        #pragma unroll 8
        for (int cc = 0; cc < 64; ++cc) {
            int c = cc * 4 + c0;
            xs[r][c ^ sw] = xb[(size_t)c * 4096];
        }
    }
    const int mg  = t >> 4;
    const int ng  = t & 15;
    const int m0  = mg * 4;
    const int nn0 = ng * 4;
    const int swm = SWZ(m0);
    const int swn = SWZ(nn0);
    float minv[4] = {1e30f, 1e30f, 1e30f, 1e30f};
    int   mini[4] = {0, 0, 0, 0};
    for (int k0 = 0; k0 < K_CODES; k0 += 64) {
        __syncthreads();
        {
            const int lane = t & 63;
            const int cw   = t >> 6;
            #pragma unroll
            for (int p = 0; p < 16; ++p) {
                int code = p * 4 + cw;
                float4 v = *(const float4*)(cb + (size_t)(k0 + code) * C_DIM + lane * 4);
                *(float4*)&es[code][(lane * 4) ^ SWZ(code)] = v;
            }
        }
        float cn[4];
        #pragma unroll
        for (int j = 0; j < 4; ++j) cn[j] = cnorm[k0 + nn0 + j];
        __syncthreads();
        float acc[4][4];
        #pragma unroll
        for (int i = 0; i < 4; ++i)
            #pragma unroll
            for (int j = 0; j < 4; ++j) acc[i][j] = 0.f;
        #pragma unroll 4
        for (int c = 0; c < C_DIM; c += 4) {
            float4 xa[4], eb[4];
            #pragma unroll
            for (int i = 0; i < 4; ++i) xa[i] = *(const float4*)&xs[m0 + i][c ^ swm];
            #pragma unroll
            for (int j = 0; j < 4; ++j) eb[j] = *(const float4*)&es[nn0 + j][c ^ swn];
            #pragma unroll
            for (int i = 0; i < 4; ++i)
                #pragma unroll
                for (int j = 0; j < 4; ++j)
                    acc[i][j] += xa[i].x * eb[j].x + xa[i].y * eb[j].y +
                                 xa[i].z * eb[j].z + xa[i].w * eb[j].w;
        }
        #pragma unroll
        for (int j = 0; j < 4; ++j) {
            const int kg = k0 + nn0 + j;
            #pragma unroll
            for (int i = 0; i < 4; ++i) {
                float dist = fmaf(-2.f, acc[i][j], cn[j]);
                if (dist < minv[i]) { minv[i] = dist; mini[i] = kg; }
            }
        }
    }
    #pragma unroll
    for (int off = 1; off < 16; off <<= 1) {
        #pragma unroll
        for (int i = 0; i < 4; ++i) {
            float ov = __shfl_xor(minv[i], off);
            int   oi = __shfl_xor(mini[i], off);
            if (ov < minv[i] || (ov == minv[i] && oi < mini[i])) { minv[i] = ov; mini[i] = oi; }
        }
    }
    if (ng == 0) {
        #pragma unroll
        for (int i = 0; i < 4; ++i) idxf[n0 + m0 + i] = (float)mini[i];
    }
}

__global__ void kquant_legacy(const float* __restrict__ x, const float* __restrict__ cb,
                              const float* __restrict__ idxf, float* __restrict__ qout,
                              float* __restrict__ dw, float* __restrict__ counts,
                              float* __restrict__ loss_arr) {
    const int t   = threadIdx.x;
    const int bid = blockIdx.x;
    const int sc  = bid & 15;
    const int c   = (bid >> 4) & 255;
    const int b   = bid >> 12;
    const int s   = sc * 256 + t;
    const int n   = b * 4096 + s;
    const int k   = (int)idxf[n];
    const size_t xoff = ((size_t)b * C_DIM + c) * 4096 + s;
    const float xv = x[xoff];
    const float q  = cb[(size_t)k * C_DIM + c];
    qout[xoff] = xv + (q - xv);
    atomicAdd(&dw[(size_t)k * C_DIM + c], xv);
    if (c == 0) atomicAdd(&counts[k], 1.0f);
    float d = q - xv;
    float p = d * d;
    #pragma unroll
    for (int off = 32; off; off >>= 1) p += __shfl_down(p, off);
    __shared__ float ps[4];
    if ((t & 63) == 0) ps[t >> 6] = p;
    __syncthreads();
    if (t == 0) atomicAdd(&loss_arr[bid & 255], ps[0] + ps[1] + ps[2] + ps[3]);
}

__global__ void kstats_legacy(const float* __restrict__ counts, const float* __restrict__ loss_arr,
                              float* __restrict__ out) {
    const int t = threadIdx.x;
    float nz = 0.f, s = 0.f;
    for (int k = t; k < K_CODES; k += 256) {
        float cnt = counts[k];
        if (cnt != 0.f) nz += 1.f;
        float p = cnt * (1.f / 32768.f);
        s += p * logf(p + 1e-10f);
    }
    float ls = loss_arr[t];
    #pragma unroll
    for (int off = 32; off; off >>= 1) {
        s  += __shfl_down(s, off);
        nz += __shfl_down(nz, off);
        ls += __shfl_down(ls, off);
    }
    __shared__ float ss[4], zz[4], ll[4];
    const int wid = t >> 6, lane = t & 63;
    if (lane == 0) { ss[wid] = s; zz[wid] = nz; ll[wid] = ls; }
    __syncthreads();
    if (t == 0) {
        out[OFF_ELOSS] = COMMITF * (ll[0] + ll[1] + ll[2] + ll[3]) / 8388608.f;
        out[OFF_PERP]  = expf(-(ss[0] + ss[1] + ss[2] + ss[3]));
        out[OFF_UNIQ]  = zz[0] + zz[1] + zz[2] + zz[3];
    }
}

__global__ void kfinal_legacy(const float* __restrict__ ema_c, const float* __restrict__ ema_w,
                              float* __restrict__ counts, float* __restrict__ dw,
                              float* __restrict__ ncb) {
    const int k = blockIdx.x;
    const int c = threadIdx.x;
    const float cnt  = counts[k];
    const float ncnt = (DECAYF * ema_c[k] + (1.f - DECAYF) * cnt + EPSF)
                       / (8.f + (float)K_CODES * EPSF) * 8.f;
    const size_t o = (size_t)k * C_DIM + c;
    const float nw = DECAYF * ema_w[o] + (1.f - DECAYF) * dw[o];
    __syncthreads();
    dw[o]  = nw;
    ncb[o] = nw / ncnt;
    if (c == 0) counts[k] = ncnt;
}

extern "C" void kernel_launch(void* const* d_in, const int* in_sizes, int n_in,
                              void* d_out, int out_size, void* d_ws, size_t ws_size,
                              hipStream_t stream) {
    const float* x     = (const float*)d_in[0];
    const float* cb    = (const float*)d_in[1];
    const float* ema_c = (const float*)d_in[2];
    const float* ema_w = (const float*)d_in[3];
    float* out = (float*)d_out;

    float* qout = out + OFF_QUANT;
    float* ncb  = out + OFF_NCB;
    float* ncnt = out + OFF_NCNT;
    float* nw   = out + OFF_NW;
    float* idxf = out + OFF_IDX;

    const size_t szA = (size_t)N_ROWS * C_DIM;    // 8388608 bytes per plane
    const size_t szB = (size_t)K_CODES * C_DIM;   // 2097152
    const size_t fcount = 8192 + 256 + 8192 + 4 + 2560;
    const size_t need = 2 * szA + 2 * szB + fcount * 4
                      + RESC_CAP * 8 + RESC_CAP * 4 + 4 + 8192 * 4 * 2 + 32768 * 4 + 64;
    const bool use_i8 = ws_size >= need;

    if (use_i8) {
        signed char* Ah = (signed char*)d_ws;
        signed char* Al = Ah + szA;
        signed char* Bh = Al + szA;
        signed char* Bl = Bh + szB;
        float* fbase      = (float*)(Bl + szB);
        float* cnorm      = fbase;
        float* loss_arr   = fbase + 8192;
        float* counts_raw = fbase + 8448;
        float* scl        = fbase + 16640;
        float* maxbuf     = fbase + 16644;
        uint2* rpair      = (uint2*)(fbase + fcount);
        unsigned* rrows   = (unsigned*)(rpair + RESC_CAP);
        unsigned* rcnt    = rrows + RESC_CAP;
        unsigned* off     = rcnt + 1;
        unsigned* cursor  = off + K_CODES;
        unsigned* rowlist = cursor + K_CODES;
        uint2* wsmin = (uint2*)(out + OFF_QUANT);   // 8.4 MB, consumed before kquant2 writes qout

        kmax<<<2560, 256, 0, stream>>>(x, cb, maxbuf);
        kscale<<<1, 256, 0, stream>>>(maxbuf, scl, counts_raw, loss_arr, rcnt);
        kprep<<<4096, 256, 0, stream>>>(cb, x, Ah, Al, Bh, Bl, cnorm, scl);
        kargmin_i8<<<8192, 512, 0, stream>>>(Ah, Al, Bh, Bl, cnorm, scl, wsmin);
        kcombine<<<N_ROWS / 256, 256, 0, stream>>>(wsmin, idxf, x, cb, cnorm, counts_raw);
        kscan<<<1, 256, 0, stream>>>(counts_raw, off, cursor);
        kscatter<<<N_ROWS / 256, 256, 0, stream>>>(idxf, cursor, rowlist);
        kquant2<<<512, 256, 0, stream>>>(x, cb, idxf, qout, loss_arr);
        kfinal3<<<K_CODES + 1, C_DIM, 0, stream>>>(ema_c, ema_w, counts_raw, off, rowlist,
                                                   Ah, Al, scl, nw, ncb, ncnt, loss_arr, out);
    } else {
        float* cnorm = (float*)d_ws;
        float* loss_arr = cnorm + K_CODES;
        hipMemsetAsync(ncnt, 0, K_CODES * sizeof(float), stream);
        hipMemsetAsync(nw, 0, (size_t)K_CODES * C_DIM * sizeof(float), stream);
        hipMemsetAsync(loss_arr, 0, 256 * sizeof(float), stream);
        knorm<<<K_CODES / 4, 256, 0, stream>>>(cb, cnorm);
        kargmin_fp32<<<N_ROWS / 64, 256, 0, stream>>>(x, cb, cnorm, idxf);
        kquant_legacy<<<32768, 256, 0, stream>>>(x, cb, idxf, qout, nw, ncnt, loss_arr);
        kstats_legacy<<<1, 256, 0, stream>>>(ncnt, loss_arr, out);
        kfinal_legacy<<<K_CODES, C_DIM, 0, stream>>>(ema_c, ema_w, ncnt, nw, ncb);
    }
}